// Round 18
// baseline (361.723 us; speedup 1.0000x reference)
//
#include <hip/hip_runtime.h>
#include <hip/hip_bf16.h>
#include <stdint.h>

typedef unsigned short u16;
typedef unsigned char u8;
typedef long i64;
typedef float f32x2 __attribute__((ext_vector_type(2)));
typedef float f32x4 __attribute__((ext_vector_type(4)));
typedef unsigned int u32x4 __attribute__((ext_vector_type(4)));

#define FEAT 512
#define BATCH 8192
#define NC1 20
#define NC2 100
#define NC3 500
#define NC4 2000
#define NC5 10000
#define NCAT 2620
#define LDP 2624          // padded leading dim for pcat (fp8 bytes, 16B-clean)
#define NTOT 12620
#define NCT 40            // l5 col tiles (by = 10..49)
#define WN_BLOCKS 3155    // ceil(12620 / 4) wnorm blocks (4 rows x 64 lanes)
#define CAST_BLOCKS 2048  // 8192*512/8/256
#define NGRP 2620         // cosine groups total
#define WCOS_BLOCKS 655   // ceil(2620 / 4)

__device__ inline u16 f2bf(float f) {
    unsigned int u = __builtin_bit_cast(unsigned int, f);
    unsigned int r = (u + 0x7FFFu + ((u >> 16) & 1u)) >> 16;
    return (u16)r;
}
__device__ inline float bfu(u16 u) {
    return __builtin_bit_cast(float, (unsigned int)u << 16);
}
// HW fp8 e4m3 (OCP on gfx950) pack/unpack
__device__ inline unsigned int pack4_fp8(float a0, float a1, float a2, float a3) {
    int v = 0;
    v = __builtin_amdgcn_cvt_pk_fp8_f32(a0, a1, v, false);
    v = __builtin_amdgcn_cvt_pk_fp8_f32(a2, a3, v, true);
    return (unsigned int)v;
}
__device__ inline f32x4 unpack4_fp8(unsigned int v) {
    f32x2 lo = __builtin_amdgcn_cvt_pk_f32_fp8((int)v, false);
    f32x2 hi = __builtin_amdgcn_cvt_pk_f32_fp8((int)v, true);
    f32x4 o; o[0] = lo[0]; o[1] = lo[1]; o[2] = hi[0]; o[3] = hi[1];
    return o;
}
__device__ inline float fp8_1(u8 u) {
    return __builtin_amdgcn_cvt_f32_fp8((int)u, 0);
}

__device__ inline float waveReduceSum(float v) {
    #pragma unroll
    for (int off = 32; off > 0; off >>= 1) v += __shfl_xor(v, off);
    return v;
}
__device__ inline float waveReduceMax(float v) {
    #pragma unroll
    for (int off = 32; off > 0; off >>= 1) v = fmaxf(v, __shfl_xor(v, off));
    return v;
}
// 256-thread blocks
__device__ inline float blockReduceSum(float v, float* sh) {
    int t = threadIdx.x;
    v = waveReduceSum(v);
    __syncthreads();
    if ((t & 63) == 0) sh[t >> 6] = v;
    __syncthreads();
    return sh[0] + sh[1] + sh[2] + sh[3];
}
// 512-thread blocks
__device__ inline float blockReduceSum8(float v, float* sh) {
    int t = threadIdx.x;
    v = waveReduceSum(v);
    __syncthreads();
    if ((t & 63) == 0) sh[t >> 6] = v;
    __syncthreads();
    return (sh[0] + sh[1]) + (sh[2] + sh[3]) + (sh[4] + sh[5]) + (sh[6] + sh[7]);
}
__device__ inline float blockReduceMax8(float v, float* sh) {
    int t = threadIdx.x;
    v = waveReduceMax(v);
    __syncthreads();
    if ((t & 63) == 0) sh[t >> 6] = v;
    __syncthreads();
    return fmaxf(fmaxf(fmaxf(sh[0], sh[1]), fmaxf(sh[2], sh[3])),
                 fmaxf(fmaxf(sh[4], sh[5]), fmaxf(sh[6], sh[7])));
}

__device__ inline void gload16(const void* g, void* l) {
    __builtin_amdgcn_global_load_lds((const __attribute__((address_space(1))) void*)g,
                                     (__attribute__((address_space(3))) void*)l, 16, 0, 0);
}

// ---------------- prep: cast x/W to fp8, l2-normalize weights, wcos terms ----------------

__global__ __launch_bounds__(256) void prep(const float* __restrict__ x, u8* __restrict__ xb8,
                                            const float* __restrict__ W1, const float* __restrict__ b1,
                                            const float* __restrict__ W2, const float* __restrict__ b2,
                                            const float* __restrict__ W3, const float* __restrict__ b3,
                                            const float* __restrict__ W4, const float* __restrict__ b4,
                                            const float* __restrict__ W5, const float* __restrict__ b5,
                                            u8* __restrict__ wb8, float* __restrict__ biascat,
                                            float* __restrict__ c45, float* __restrict__ c34,
                                            float* __restrict__ c23, float* __restrict__ c12) {
    int bid = blockIdx.x;
    if (bid < WN_BLOCKS) {
        int r = bid * 4 + (threadIdx.x >> 6);
        if (r >= NTOT) return;
        int t = threadIdx.x & 63;
        const float* W; const float* b; int lr;
        if      (r < 20)   { W = W1; b = b1; lr = r; }
        else if (r < 120)  { W = W2; b = b2; lr = r - 20; }
        else if (r < 620)  { W = W3; b = b3; lr = r - 120; }
        else if (r < 2620) { W = W4; b = b4; lr = r - 620; }
        else               { W = W5; b = b5; lr = r - 2620; }
        const float* p = W + (size_t)lr * FEAT + t * 8;
        float v[8]; float ss = 0.f;
        #pragma unroll
        for (int j = 0; j < 8; ++j) { v[j] = p[j]; ss += v[j] * v[j]; }
        ss = waveReduceSum(ss);
        float inv = 1.0f / fmaxf(sqrtf(ss), 1e-12f);
        uint2 o;
        o.x = pack4_fp8(v[0] * inv, v[1] * inv, v[2] * inv, v[3] * inv);
        o.y = pack4_fp8(v[4] * inv, v[5] * inv, v[6] * inv, v[7] * inv);
        *reinterpret_cast<uint2*>(wb8 + (size_t)r * FEAT + t * 8) = o;
        if (t == 0) biascat[r] = b[lr];
    } else if (bid < WN_BLOCKS + CAST_BLOCKS) {
        int i = (bid - WN_BLOCKS) * 256 + threadIdx.x;
        const float* p = x + (size_t)i * 8;
        uint2 o;
        o.x = pack4_fp8(p[0], p[1], p[2], p[3]);
        o.y = pack4_fp8(p[4], p[5], p[6], p[7]);
        *reinterpret_cast<uint2*>(xb8 + (size_t)i * 8) = o;
    } else {
        // weight-cosine terms: one wave per group, 4 groups per block (raw f32 W)
        int g = (bid - WN_BLOCKS - CAST_BLOCKS) * 4 + (threadIdx.x >> 6);
        if (g >= NGRP) return;
        int t = threadIdx.x & 63;
        const float* Wp; const float* Wc; int fan, j; float* dst;
        if      (g < 2000) { Wp = W4; Wc = W5; fan = 5; dst = c45; j = g; }
        else if (g < 2500) { Wp = W3; Wc = W4; fan = 4; dst = c34; j = g - 2000; }
        else if (g < 2600) { Wp = W2; Wc = W3; fan = 5; dst = c23; j = g - 2500; }
        else               { Wp = W1; Wc = W2; fan = 5; dst = c12; j = g - 2600; }

        float hat[8] = {0, 0, 0, 0, 0, 0, 0, 0};
        for (int c = 0; c < fan; ++c) {
            const float* cr = Wc + ((size_t)(j * fan + c)) * FEAT + t * 8;
            float v[8]; float ss = 0.f;
            #pragma unroll
            for (int i = 0; i < 8; ++i) { v[i] = cr[i]; ss += v[i] * v[i]; }
            ss = waveReduceSum(ss);
            float inv = 1.0f / fmaxf(sqrtf(ss), 1e-12f);
            #pragma unroll
            for (int i = 0; i < 8; ++i) hat[i] += v[i] * inv;
        }
        float hs = 0.f;
        #pragma unroll
        for (int i = 0; i < 8; ++i) hs += hat[i] * hat[i];
        hs = waveReduceSum(hs);
        float hinv = 1.0f / fmaxf(sqrtf(hs), 1e-12f);
        const float* pr = Wp + (size_t)j * FEAT + t * 8;
        float ps = 0.f, dot = 0.f;
        #pragma unroll
        for (int i = 0; i < 8; ++i) { float pv = pr[i]; ps += pv * pv; dot += pv * hat[i]; }
        ps = waveReduceSum(ps);
        dot = waveReduceSum(dot);
        if (t == 0) dst[j] = dot * hinv / fmaxf(sqrtf(ps), 1e-12f);
    }
}

// ---------------- fp8 GEMM over all 12620 columns ----------------
// 256x256 tile, 8 waves (2x4), BK=64, mfma_f32_16x16x32_fp8_fp8.
// LDS: 2 x 32 KB dbuf; per-buffer [region][kh][p][row][16B], linear staging.
// Staggered pipeline, vmcnt(2)/k-half. Outputs: cols < NCAT -> pcat (fp8!);
// cols >= NCAT -> l5f8 (fp8) + softmax partials (by >= 10).

#define BM 256
#define BN 256
#define BK 64
#define KITERS (FEAT / BK)

__global__ __launch_bounds__(512, 2) void gemm_all(const u8* __restrict__ A, const u8* __restrict__ Bw,
                                                   const float* __restrict__ bias,
                                                   u8* __restrict__ pcat, u8* __restrict__ l5f8,
                                                   float* __restrict__ pmax, float* __restrict__ psum) {
    __shared__ uint4 sABq[2][2048];            // 2 x 32 KB double buffer
    const int t = threadIdx.x;
    const int lane = t & 63, wid = t >> 6;
    const int lane15 = lane & 15, q = lane >> 4;
    const int wr = wid >> 2, wcol = wid & 3;

    // XCD-aware bijective swizzle (nwg = 32*50 = 1600, %8 == 0)
    int nwg = gridDim.x * gridDim.y;
    int lid = blockIdx.y * gridDim.x + blockIdx.x;
    int cpx = nwg >> 3;
    int swz = (lid & 7) * cpx + (lid >> 3);
    int bx = swz % gridDim.x, by = swz / gridDim.x;
    const int r0 = bx * BM, c0 = by * BN;

    f32x4 acc[8][4];
    #pragma unroll
    for (int m = 0; m < 8; ++m)
        #pragma unroll
        for (int n = 0; n < 4; ++n) acc[m][n] = f32x4{0.f, 0.f, 0.f, 0.f};

    // stage one unit (region, kh): 512 chunks of 16B, 1 per thread, LINEAR dest
    auto stageUnit = [&](char* nb, int region, int kh, int ktB) {
        int row = t & 255, p = t >> 8;
        int srck = ktB + kh * 32 + p * 16;
        const u8* g;
        if (region == 0) {
            g = A + (size_t)(r0 + row) * FEAT + srck;
        } else {
            int br = c0 + row; if (br >= NTOT) br = NTOT - 1;
            g = Bw + (size_t)br * FEAT + srck;
        }
        gload16(g, nb + region * 16384 + kh * 8192 + (size_t)t * 16);
    };

    // fragment reads: 8 fp8 (b64) at row r; k offset q*8 = (q>>1)*16 + (q&1)*8
    auto readA = [&](char* sb, int ks, int mh, i64* af) {
        #pragma unroll
        for (int i = 0; i < 4; ++i) {
            int row = wr * 128 + (mh * 4 + i) * 16 + lane15;
            af[i] = *reinterpret_cast<const i64*>(sb + ks * 8192 + (q >> 1) * 4096 +
                                                  row * 16 + (q & 1) * 8);
        }
    };
    auto readB = [&](char* sb, int ks, i64* bv) {
        #pragma unroll
        for (int n = 0; n < 4; ++n) {
            int row = wcol * 64 + n * 16 + lane15;
            bv[n] = *reinterpret_cast<const i64*>(sb + 16384 + ks * 8192 + (q >> 1) * 4096 +
                                                  row * 16 + (q & 1) * 8);
        }
    };

    // prologue: tile 0's four units, oldest-first {A-k0, B-k0, A-k1, B-k1}
    {
        char* nb = (char*)sABq[0];
        stageUnit(nb, 0, 0, 0);
        stageUnit(nb, 1, 0, 0);
        stageUnit(nb, 0, 1, 0);
        stageUnit(nb, 1, 1, 0);
    }

    for (int T = 0; T < KITERS; ++T) {
        char* sb = (char*)sABq[T & 1];
        char* nb = (char*)sABq[(T + 1) & 1];
        const bool more = (T + 1 < KITERS);
        const int ktB = (T + 1) * BK;

        // ---- k-half 0 ----
        asm volatile("s_waitcnt vmcnt(2)" ::: "memory");
        __builtin_amdgcn_sched_barrier(0);
        __builtin_amdgcn_s_barrier();
        __builtin_amdgcn_sched_barrier(0);
        {
            i64 bv[4], af[4];
            readB(sb, 0, bv);
            readA(sb, 0, 0, af);
            if (more) stageUnit(nb, 0, 0, ktB);
            __builtin_amdgcn_sched_barrier(0);
            __builtin_amdgcn_s_setprio(1);
            #pragma unroll
            for (int i = 0; i < 4; ++i)
                #pragma unroll
                for (int n = 0; n < 4; ++n)
                    acc[i][n] = __builtin_amdgcn_mfma_f32_16x16x32_fp8_fp8(bv[n], af[i], acc[i][n], 0, 0, 0);
            __builtin_amdgcn_s_setprio(0);
            __builtin_amdgcn_sched_barrier(0);
            readA(sb, 0, 1, af);
            if (more) stageUnit(nb, 1, 0, ktB);
            __builtin_amdgcn_sched_barrier(0);
            __builtin_amdgcn_s_setprio(1);
            #pragma unroll
            for (int i = 0; i < 4; ++i)
                #pragma unroll
                for (int n = 0; n < 4; ++n)
                    acc[4 + i][n] = __builtin_amdgcn_mfma_f32_16x16x32_fp8_fp8(bv[n], af[i], acc[4 + i][n], 0, 0, 0);
            __builtin_amdgcn_s_setprio(0);
            __builtin_amdgcn_sched_barrier(0);
        }

        // ---- k-half 1 ----
        if (more) { asm volatile("s_waitcnt vmcnt(2)" ::: "memory"); }
        else      { asm volatile("s_waitcnt vmcnt(0)" ::: "memory"); }
        __builtin_amdgcn_sched_barrier(0);
        __builtin_amdgcn_s_barrier();
        __builtin_amdgcn_sched_barrier(0);
        {
            i64 bv[4], af[4];
            readB(sb, 1, bv);
            readA(sb, 1, 0, af);
            if (more) stageUnit(nb, 0, 1, ktB);
            __builtin_amdgcn_sched_barrier(0);
            __builtin_amdgcn_s_setprio(1);
            #pragma unroll
            for (int i = 0; i < 4; ++i)
                #pragma unroll
                for (int n = 0; n < 4; ++n)
                    acc[i][n] = __builtin_amdgcn_mfma_f32_16x16x32_fp8_fp8(bv[n], af[i], acc[i][n], 0, 0, 0);
            __builtin_amdgcn_s_setprio(0);
            __builtin_amdgcn_sched_barrier(0);
            readA(sb, 1, 1, af);
            if (more) stageUnit(nb, 1, 1, ktB);
            __builtin_amdgcn_sched_barrier(0);
            __builtin_amdgcn_s_setprio(1);
            #pragma unroll
            for (int i = 0; i < 4; ++i)
                #pragma unroll
                for (int n = 0; n < 4; ++n)
                    acc[4 + i][n] = __builtin_amdgcn_mfma_f32_16x16x32_fp8_fp8(bv[n], af[i], acc[4 + i][n], 0, 0, 0);
            __builtin_amdgcn_s_setprio(0);
            __builtin_amdgcn_sched_barrier(0);
        }
    }

    // transposed D layout: lane holds row = r0+wr*128+m*16+lane15,
    // cols cb..cb+3 with cb = c0+wcol*64+n*16+q*4
    bool vld[4], svld[4]; int cb[4];
    #pragma unroll
    for (int n = 0; n < 4; ++n) {
        cb[n] = c0 + wcol * 64 + n * 16 + q * 4;
        vld[n] = (cb[n] < NTOT);
        svld[n] = vld[n] && (cb[n] >= NCAT);
        if (vld[n]) {
            float b0 = bias[cb[n]], b1 = bias[cb[n] + 1], b2 = bias[cb[n] + 2], b3 = bias[cb[n] + 3];
            #pragma unroll
            for (int m = 0; m < 8; ++m) {
                acc[m][n][0] += b0; acc[m][n][1] += b1;
                acc[m][n][2] += b2; acc[m][n][3] += b3;
            }
        }
    }

    if (by >= 10) {   // softmax partials for the l5 region
        float* fmx = (float*)sABq;           // [256][4] row-max per wcol
        float* fsm = fmx + 1024;             // [256][4] row-sumexp per wcol
        float bm[8];
        #pragma unroll
        for (int m = 0; m < 8; ++m) {
            float v = -1e30f;
            #pragma unroll
            for (int n = 0; n < 4; ++n)
                if (svld[n]) {
                    #pragma unroll
                    for (int j = 0; j < 4; ++j) v = fmaxf(v, acc[m][n][j]);
                }
            v = fmaxf(v, __shfl_xor(v, 16));
            v = fmaxf(v, __shfl_xor(v, 32));
            bm[m] = v;
        }
        __syncthreads();
        if (lane < 16) {
            #pragma unroll
            for (int m = 0; m < 8; ++m)
                fmx[(wr * 128 + m * 16 + lane15) * 4 + wcol] = bm[m];
        }
        __syncthreads();
        #pragma unroll
        for (int m = 0; m < 8; ++m) {
            int row = wr * 128 + m * 16 + lane15;
            bm[m] = fmaxf(fmaxf(fmx[row * 4], fmx[row * 4 + 1]),
                          fmaxf(fmx[row * 4 + 2], fmx[row * 4 + 3]));
        }
        float sm[8];
        #pragma unroll
        for (int m = 0; m < 8; ++m) {
            float s = 0.f;
            #pragma unroll
            for (int n = 0; n < 4; ++n)
                if (svld[n]) {
                    #pragma unroll
                    for (int j = 0; j < 4; ++j) s += __expf(acc[m][n][j] - bm[m]);
                }
            s += __shfl_xor(s, 16);
            s += __shfl_xor(s, 32);
            sm[m] = s;
        }
        if (lane < 16) {
            #pragma unroll
            for (int m = 0; m < 8; ++m)
                fsm[(wr * 128 + m * 16 + lane15) * 4 + wcol] = sm[m];
        }
        __syncthreads();
        if (t < 256) {
            float m4 = fmaxf(fmaxf(fmx[t * 4], fmx[t * 4 + 1]), fmaxf(fmx[t * 4 + 2], fmx[t * 4 + 3]));
            float s4 = fsm[t * 4] + fsm[t * 4 + 1] + fsm[t * 4 + 2] + fsm[t * 4 + 3];
            size_t idx = (size_t)(r0 + t) * NCT + (by - 10);
            pmax[idx] = m4;
            psum[idx] = s4;
        }
    }

    // store: both regions fp8 as HW-packed uint (4 cols x 1B)
    #pragma unroll
    for (int m = 0; m < 8; ++m) {
        int row = r0 + wr * 128 + m * 16 + lane15;
        #pragma unroll
        for (int n = 0; n < 4; ++n) {
            if (vld[n]) {
                unsigned int v = pack4_fp8(acc[m][n][0], acc[m][n][1], acc[m][n][2], acc[m][n][3]);
                u8* dst = (cb[n] < NCAT)
                    ? &pcat[(size_t)row * LDP + cb[n]]
                    : &l5f8[(size_t)row * NC5 + (cb[n] - NCAT)];
                *reinterpret_cast<unsigned int*>(dst) = v;
            }
        }
    }
}

// ---------------- fused LSE + CE + probabilities + all JSDs (512-thread block per row) ----------------

__global__ __launch_bounds__(512) void probs_all(const u8* __restrict__ l5f8, float* __restrict__ out,
                                                 const u8* __restrict__ pcat,
                                                 const float* __restrict__ pmax, const float* __restrict__ psum,
                                                 const int* __restrict__ tgt,
                                                 float* __restrict__ cerow,
                                                 float* __restrict__ j12, float* __restrict__ j23,
                                                 float* __restrict__ j34, float* __restrict__ j45) {
    __shared__ u16 P5[NC5];
    __shared__ float PC[NCAT];
    __shared__ float sh[8];
    __shared__ float shls;
    int b = blockIdx.x, t = threadIdx.x;
    float* orow = out + (size_t)b * NC5;
    const u8* lrow = l5f8 + (size_t)b * NC5;
    const u8* prow = pcat + (size_t)b * LDP;

    // wave 0: reduce the per-coltile partials into the row LSE
    if (t < 64) {
        float pm = (t < NCT) ? pmax[(size_t)b * NCT + t] : -1e30f;
        float ps = (t < NCT) ? psum[(size_t)b * NCT + t] : 0.f;
        float gm = waveReduceMax(pm);
        float s = waveReduceSum(ps * __expf(pm - gm));
        if (t == 0) {
            float ls = gm + __logf(s);
            shls = ls;
            int tg = tgt[b];
            cerow[b] = -(fp8_1(lrow[tg]) - ls);
        }
    }
    // stage pcat row (fp8) into LDS as f32: 328 items of 8
    for (int c = t; c < LDP / 8; c += 512) {
        uint2 raw = ((const uint2*)prow)[c];
        f32x4 a = unpack4_fp8(raw.x);
        f32x4 bb = unpack4_fp8(raw.y);
        int base = c * 8;
        #pragma unroll
        for (int k = 0; k < 4; ++k) if (base + k < NCAT) PC[base + k] = a[k];
        #pragma unroll
        for (int k = 0; k < 4; ++k) if (base + 4 + k < NCAT) PC[base + 4 + k] = bb[k];
    }
    __syncthreads();
    float ls = shls;

    // l5 row: 1250 items of 8 fp8 (uint2 cached load); two f32x4 NT stores
    for (int c = t; c < NC5 / 8; c += 512) {
        uint2 raw = ((const uint2*)lrow)[c];
        f32x4 l0 = unpack4_fp8(raw.x);
        f32x4 l1 = unpack4_fp8(raw.y);
        f32x4 o0, o1;
        #pragma unroll
        for (int k = 0; k < 4; ++k) o0[k] = __expf(l0[k] - ls);
        #pragma unroll
        for (int k = 0; k < 4; ++k) o1[k] = __expf(l1[k] - ls);
        __builtin_nontemporal_store(o0, &((f32x4*)orow)[c * 2]);
        __builtin_nontemporal_store(o1, &((f32x4*)orow)[c * 2 + 1]);
        union { u16 u[8]; uint4 v; } pk;
        #pragma unroll
        for (int k = 0; k < 4; ++k) pk.u[k] = f2bf(o0[k]);
        #pragma unroll
        for (int k = 0; k < 4; ++k) pk.u[4 + k] = f2bf(o1[k]);
        ((uint4*)P5)[c] = pk.v;
    }
    __syncthreads();

    auto softmax_seg = [&](int off, int C) {
        float m = -1e30f;
        for (int c = t; c < C; c += 512) m = fmaxf(m, PC[off + c]);
        m = blockReduceMax8(m, sh);
        float s = 0.f;
        for (int c = t; c < C; c += 512) { float e = __expf(PC[off + c] - m); PC[off + c] = e; s += e; }
        s = blockReduceSum8(s, sh);
        float inv = 1.0f / s;
        for (int c = t; c < C; c += 512) PC[off + c] *= inv;
    };
    softmax_seg(0, NC1);
    softmax_seg(20, NC2);
    softmax_seg(120, NC3);
    softmax_seg(620, NC4);
    __syncthreads();

    {   // jsd45: agg p5 (fan 5) vs p4
        float klpm = 0.f, klqm = 0.f;
        for (int g = t; g < NC4; g += 512) {
            float qv = 0.f;
            #pragma unroll
            for (int f = 0; f < 5; ++f) qv += bfu(P5[5 * g + f]);
            float pp = PC[620 + g];
            float mm = 0.5f * (qv + pp);
            float lm = __logf(mm + 1e-8f);
            klpm += qv * (__logf(qv + 1e-8f) - lm);
            klqm += pp * (__logf(pp + 1e-8f) - lm);
        }
        float tot = blockReduceSum8(0.5f * (klpm + klqm), sh);
        if (t == 0) j45[b] = tot;
    }
    auto jsd_seg = [&](int childOff, int fan, int parentOff, int nPar, float* dst) {
        float klpm = 0.f, klqm = 0.f;
        for (int g = t; g < nPar; g += 512) {
            float qv = 0.f;
            for (int f = 0; f < fan; ++f) qv += PC[childOff + g * fan + f];
            float pp = PC[parentOff + g];
            float mm = 0.5f * (qv + pp);
            float lm = __logf(mm + 1e-8f);
            klpm += qv * (__logf(qv + 1e-8f) - lm);
            klqm += pp * (__logf(pp + 1e-8f) - lm);
        }
        float tot = blockReduceSum8(0.5f * (klpm + klqm), sh);
        if (t == 0) dst[b] = tot;
    };
    jsd_seg(620, 4, 120, NC3, j34);
    jsd_seg(120, 5, 20, NC2, j23);
    jsd_seg(20, 5, 0, NC1, j12);
}

__global__ __launch_bounds__(256) void finalize(const float* __restrict__ ce, const float* __restrict__ j45,
                                                const float* __restrict__ j34, const float* __restrict__ j23,
                                                const float* __restrict__ j12, const float* __restrict__ c45,
                                                const float* __restrict__ c34, const float* __restrict__ c23,
                                                const float* __restrict__ c12, float* __restrict__ lossOut) {
    __shared__ float sh[4];
    auto meanArr = [&](const float* a, int n) {
        float s = 0.f;
        for (int i = threadIdx.x; i < n; i += 256) s += a[i];
        s = blockReduceSum(s, sh);
        return s / n;
    };
    float loss = meanArr(ce, BATCH);
    loss += meanArr(j45, BATCH) + meanArr(j34, BATCH) + meanArr(j23, BATCH) + meanArr(j12, BATCH);
    loss -= meanArr(c45, NC4) + meanArr(c34, NC3) + meanArr(c23, NC2) + meanArr(c12, NC1);
    if (threadIdx.x == 0) *lossOut = loss;
}

// ---------------- launch ----------------

extern "C" void kernel_launch(void* const* d_in, const int* in_sizes, int n_in,
                              void* d_out, int out_size, void* d_ws, size_t ws_size,
                              hipStream_t stream) {
    const float* x  = (const float*)d_in[0];
    const int*   tg = (const int*)d_in[1];
    const float* W1 = (const float*)d_in[2];  const float* b1 = (const float*)d_in[3];
    const float* W2 = (const float*)d_in[4];  const float* b2 = (const float*)d_in[5];
    const float* W3 = (const float*)d_in[6];  const float* b3 = (const float*)d_in[7];
    const float* W4 = (const float*)d_in[8];  const float* b4 = (const float*)d_in[9];
    const float* W5 = (const float*)d_in[10]; const float* b5 = (const float*)d_in[11];
    float* out = (float*)d_out;

    char* ws = (char*)d_ws;
    size_t off = 0;
    auto alloc = [&](size_t bytes) { void* p = ws + off; off = (off + bytes + 255) & ~(size_t)255; return p; };
    u8*    xb8     = (u8*)alloc((size_t)BATCH * FEAT);
    u8*    wb8     = (u8*)alloc((size_t)NTOT * FEAT);
    float* biascat = (float*)alloc((size_t)NTOT * 4);
    u8*    pcat    = (u8*)alloc((size_t)BATCH * LDP);
    u8*    l5f8    = (u8*)alloc((size_t)BATCH * NC5);
    float* pmax    = (float*)alloc((size_t)BATCH * NCT * 4);
    float* psum    = (float*)alloc((size_t)BATCH * NCT * 4);
    float* cerow   = (float*)alloc((size_t)BATCH * 4);
    float* j45     = (float*)alloc((size_t)BATCH * 4);
    float* j34     = (float*)alloc((size_t)BATCH * 4);
    float* j23     = (float*)alloc((size_t)BATCH * 4);
    float* j12     = (float*)alloc((size_t)BATCH * 4);
    float* c45     = (float*)alloc((size_t)NC4 * 4);
    float* c34     = (float*)alloc((size_t)NC3 * 4);
    float* c23     = (float*)alloc((size_t)NC2 * 4);
    float* c12     = (float*)alloc((size_t)NC1 * 4);

    prep<<<WN_BLOCKS + CAST_BLOCKS + WCOS_BLOCKS, 256, 0, stream>>>(
        x, xb8, W1, b1, W2, b2, W3, b3, W4, b4, W5, b5, wb8, biascat, c45, c34, c23, c12);

    gemm_all<<<dim3(BATCH / BM, (NTOT + BN - 1) / BN), 512, 0, stream>>>(
        xb8, wb8, biascat, pcat, l5f8, pmax, psum);

    probs_all<<<BATCH, 512, 0, stream>>>(l5f8, out, pcat, pmax, psum, tg, cerow,
                                         j12, j23, j34, j45);

    finalize<<<1, 256, 0, stream>>>(cerow, j45, j34, j23, j12, c45, c34, c23, c12,
                                    out + (size_t)BATCH * NC5);
}

// Round 19
// 344.009 us; speedup vs baseline: 1.0515x; 1.0515x over previous
//
#include <hip/hip_runtime.h>
#include <hip/hip_bf16.h>
#include <stdint.h>

typedef unsigned short u16;
typedef unsigned char u8;
typedef long i64;
typedef float f32x2 __attribute__((ext_vector_type(2)));
typedef float f32x4 __attribute__((ext_vector_type(4)));
typedef unsigned int u32x4 __attribute__((ext_vector_type(4)));

#define FEAT 512
#define BATCH 8192
#define NC1 20
#define NC2 100
#define NC3 500
#define NC4 2000
#define NC5 10000
#define NCAT 2620
#define LDP 2624          // padded leading dim for pcat (fp8 bytes, 16B-clean)
#define NTOT 12620
#define NCT 40            // l5 col tiles (by = 10..49)
#define WN_BLOCKS 3155    // ceil(12620 / 4) wnorm blocks (4 rows x 64 lanes)
#define CAST_BLOCKS 2048  // 8192*512/8/256
#define NGRP 2620         // cosine groups total
#define WCOS_BLOCKS 655   // ceil(2620 / 4)

__device__ inline u16 f2bf(float f) {
    unsigned int u = __builtin_bit_cast(unsigned int, f);
    unsigned int r = (u + 0x7FFFu + ((u >> 16) & 1u)) >> 16;
    return (u16)r;
}
__device__ inline float bfu(u16 u) {
    return __builtin_bit_cast(float, (unsigned int)u << 16);
}
// HW fp8 e4m3 (OCP on gfx950) pack/unpack
__device__ inline unsigned int pack4_fp8(float a0, float a1, float a2, float a3) {
    int v = 0;
    v = __builtin_amdgcn_cvt_pk_fp8_f32(a0, a1, v, false);
    v = __builtin_amdgcn_cvt_pk_fp8_f32(a2, a3, v, true);
    return (unsigned int)v;
}
__device__ inline f32x4 unpack4_fp8(unsigned int v) {
    f32x2 lo = __builtin_amdgcn_cvt_pk_f32_fp8((int)v, false);
    f32x2 hi = __builtin_amdgcn_cvt_pk_f32_fp8((int)v, true);
    f32x4 o; o[0] = lo[0]; o[1] = lo[1]; o[2] = hi[0]; o[3] = hi[1];
    return o;
}
__device__ inline float fp8_1(u8 u) {
    return __builtin_amdgcn_cvt_f32_fp8((int)u, 0);
}

__device__ inline float waveReduceSum(float v) {
    #pragma unroll
    for (int off = 32; off > 0; off >>= 1) v += __shfl_xor(v, off);
    return v;
}
__device__ inline float waveReduceMax(float v) {
    #pragma unroll
    for (int off = 32; off > 0; off >>= 1) v = fmaxf(v, __shfl_xor(v, off));
    return v;
}
// 256-thread blocks
__device__ inline float blockReduceSum(float v, float* sh) {
    int t = threadIdx.x;
    v = waveReduceSum(v);
    __syncthreads();
    if ((t & 63) == 0) sh[t >> 6] = v;
    __syncthreads();
    return sh[0] + sh[1] + sh[2] + sh[3];
}
__device__ inline float blockReduceMax(float v, float* sh) {
    int t = threadIdx.x;
    v = waveReduceMax(v);
    __syncthreads();
    if ((t & 63) == 0) sh[t >> 6] = v;
    __syncthreads();
    return fmaxf(fmaxf(sh[0], sh[1]), fmaxf(sh[2], sh[3]));
}

__device__ inline void gload16(const void* g, void* l) {
    __builtin_amdgcn_global_load_lds((const __attribute__((address_space(1))) void*)g,
                                     (__attribute__((address_space(3))) void*)l, 16, 0, 0);
}

// ---------------- prep: cast x/W to fp8, l2-normalize weights, wcos terms ----------------

__global__ __launch_bounds__(256) void prep(const float* __restrict__ x, u8* __restrict__ xb8,
                                            const float* __restrict__ W1, const float* __restrict__ b1,
                                            const float* __restrict__ W2, const float* __restrict__ b2,
                                            const float* __restrict__ W3, const float* __restrict__ b3,
                                            const float* __restrict__ W4, const float* __restrict__ b4,
                                            const float* __restrict__ W5, const float* __restrict__ b5,
                                            u8* __restrict__ wb8, float* __restrict__ biascat,
                                            float* __restrict__ c45, float* __restrict__ c34,
                                            float* __restrict__ c23, float* __restrict__ c12) {
    int bid = blockIdx.x;
    if (bid < WN_BLOCKS) {
        int r = bid * 4 + (threadIdx.x >> 6);
        if (r >= NTOT) return;
        int t = threadIdx.x & 63;
        const float* W; const float* b; int lr;
        if      (r < 20)   { W = W1; b = b1; lr = r; }
        else if (r < 120)  { W = W2; b = b2; lr = r - 20; }
        else if (r < 620)  { W = W3; b = b3; lr = r - 120; }
        else if (r < 2620) { W = W4; b = b4; lr = r - 620; }
        else               { W = W5; b = b5; lr = r - 2620; }
        const float* p = W + (size_t)lr * FEAT + t * 8;
        float v[8]; float ss = 0.f;
        #pragma unroll
        for (int j = 0; j < 8; ++j) { v[j] = p[j]; ss += v[j] * v[j]; }
        ss = waveReduceSum(ss);
        float inv = 1.0f / fmaxf(sqrtf(ss), 1e-12f);
        uint2 o;
        o.x = pack4_fp8(v[0] * inv, v[1] * inv, v[2] * inv, v[3] * inv);
        o.y = pack4_fp8(v[4] * inv, v[5] * inv, v[6] * inv, v[7] * inv);
        *reinterpret_cast<uint2*>(wb8 + (size_t)r * FEAT + t * 8) = o;
        if (t == 0) biascat[r] = b[lr];
    } else if (bid < WN_BLOCKS + CAST_BLOCKS) {
        int i = (bid - WN_BLOCKS) * 256 + threadIdx.x;
        const float* p = x + (size_t)i * 8;
        uint2 o;
        o.x = pack4_fp8(p[0], p[1], p[2], p[3]);
        o.y = pack4_fp8(p[4], p[5], p[6], p[7]);
        *reinterpret_cast<uint2*>(xb8 + (size_t)i * 8) = o;
    } else {
        // weight-cosine terms: one wave per group, 4 groups per block (raw f32 W)
        int g = (bid - WN_BLOCKS - CAST_BLOCKS) * 4 + (threadIdx.x >> 6);
        if (g >= NGRP) return;
        int t = threadIdx.x & 63;
        const float* Wp; const float* Wc; int fan, j; float* dst;
        if      (g < 2000) { Wp = W4; Wc = W5; fan = 5; dst = c45; j = g; }
        else if (g < 2500) { Wp = W3; Wc = W4; fan = 4; dst = c34; j = g - 2000; }
        else if (g < 2600) { Wp = W2; Wc = W3; fan = 5; dst = c23; j = g - 2500; }
        else               { Wp = W1; Wc = W2; fan = 5; dst = c12; j = g - 2600; }

        float hat[8] = {0, 0, 0, 0, 0, 0, 0, 0};
        for (int c = 0; c < fan; ++c) {
            const float* cr = Wc + ((size_t)(j * fan + c)) * FEAT + t * 8;
            float v[8]; float ss = 0.f;
            #pragma unroll
            for (int i = 0; i < 8; ++i) { v[i] = cr[i]; ss += v[i] * v[i]; }
            ss = waveReduceSum(ss);
            float inv = 1.0f / fmaxf(sqrtf(ss), 1e-12f);
            #pragma unroll
            for (int i = 0; i < 8; ++i) hat[i] += v[i] * inv;
        }
        float hs = 0.f;
        #pragma unroll
        for (int i = 0; i < 8; ++i) hs += hat[i] * hat[i];
        hs = waveReduceSum(hs);
        float hinv = 1.0f / fmaxf(sqrtf(hs), 1e-12f);
        const float* pr = Wp + (size_t)j * FEAT + t * 8;
        float ps = 0.f, dot = 0.f;
        #pragma unroll
        for (int i = 0; i < 8; ++i) { float pv = pr[i]; ps += pv * pv; dot += pv * hat[i]; }
        ps = waveReduceSum(ps);
        dot = waveReduceSum(dot);
        if (t == 0) dst[j] = dot * hinv / fmaxf(sqrtf(ps), 1e-12f);
    }
}

// ---------------- fp8 GEMM over all 12620 columns ----------------
// 256x256 tile, 8 waves (2x4), BK=64, mfma_f32_16x16x32_fp8_fp8.
// LDS: 2 x 32 KB dbuf; per-buffer [region][kh][p][row][16B], linear staging.
// Staggered pipeline, vmcnt(2)/k-half. Outputs: cols < NCAT -> pcat (fp8);
// cols >= NCAT -> l5f8 (fp8) + softmax partials (by >= 10).

#define BM 256
#define BN 256
#define BK 64
#define KITERS (FEAT / BK)

__global__ __launch_bounds__(512, 2) void gemm_all(const u8* __restrict__ A, const u8* __restrict__ Bw,
                                                   const float* __restrict__ bias,
                                                   u8* __restrict__ pcat, u8* __restrict__ l5f8,
                                                   float* __restrict__ pmax, float* __restrict__ psum) {
    __shared__ uint4 sABq[2][2048];            // 2 x 32 KB double buffer
    const int t = threadIdx.x;
    const int lane = t & 63, wid = t >> 6;
    const int lane15 = lane & 15, q = lane >> 4;
    const int wr = wid >> 2, wcol = wid & 3;

    // XCD-aware bijective swizzle (nwg = 32*50 = 1600, %8 == 0)
    int nwg = gridDim.x * gridDim.y;
    int lid = blockIdx.y * gridDim.x + blockIdx.x;
    int cpx = nwg >> 3;
    int swz = (lid & 7) * cpx + (lid >> 3);
    int bx = swz % gridDim.x, by = swz / gridDim.x;
    const int r0 = bx * BM, c0 = by * BN;

    f32x4 acc[8][4];
    #pragma unroll
    for (int m = 0; m < 8; ++m)
        #pragma unroll
        for (int n = 0; n < 4; ++n) acc[m][n] = f32x4{0.f, 0.f, 0.f, 0.f};

    // stage one unit (region, kh): 512 chunks of 16B, 1 per thread, LINEAR dest
    auto stageUnit = [&](char* nb, int region, int kh, int ktB) {
        int row = t & 255, p = t >> 8;
        int srck = ktB + kh * 32 + p * 16;
        const u8* g;
        if (region == 0) {
            g = A + (size_t)(r0 + row) * FEAT + srck;
        } else {
            int br = c0 + row; if (br >= NTOT) br = NTOT - 1;
            g = Bw + (size_t)br * FEAT + srck;
        }
        gload16(g, nb + region * 16384 + kh * 8192 + (size_t)t * 16);
    };

    // fragment reads: 8 fp8 (b64) at row r; k offset q*8 = (q>>1)*16 + (q&1)*8
    auto readA = [&](char* sb, int ks, int mh, i64* af) {
        #pragma unroll
        for (int i = 0; i < 4; ++i) {
            int row = wr * 128 + (mh * 4 + i) * 16 + lane15;
            af[i] = *reinterpret_cast<const i64*>(sb + ks * 8192 + (q >> 1) * 4096 +
                                                  row * 16 + (q & 1) * 8);
        }
    };
    auto readB = [&](char* sb, int ks, i64* bv) {
        #pragma unroll
        for (int n = 0; n < 4; ++n) {
            int row = wcol * 64 + n * 16 + lane15;
            bv[n] = *reinterpret_cast<const i64*>(sb + 16384 + ks * 8192 + (q >> 1) * 4096 +
                                                  row * 16 + (q & 1) * 8);
        }
    };

    // prologue: tile 0's four units, oldest-first {A-k0, B-k0, A-k1, B-k1}
    {
        char* nb = (char*)sABq[0];
        stageUnit(nb, 0, 0, 0);
        stageUnit(nb, 1, 0, 0);
        stageUnit(nb, 0, 1, 0);
        stageUnit(nb, 1, 1, 0);
    }

    for (int T = 0; T < KITERS; ++T) {
        char* sb = (char*)sABq[T & 1];
        char* nb = (char*)sABq[(T + 1) & 1];
        const bool more = (T + 1 < KITERS);
        const int ktB = (T + 1) * BK;

        // ---- k-half 0 ----
        asm volatile("s_waitcnt vmcnt(2)" ::: "memory");
        __builtin_amdgcn_sched_barrier(0);
        __builtin_amdgcn_s_barrier();
        __builtin_amdgcn_sched_barrier(0);
        {
            i64 bv[4], af[4];
            readB(sb, 0, bv);
            readA(sb, 0, 0, af);
            if (more) stageUnit(nb, 0, 0, ktB);
            __builtin_amdgcn_sched_barrier(0);
            __builtin_amdgcn_s_setprio(1);
            #pragma unroll
            for (int i = 0; i < 4; ++i)
                #pragma unroll
                for (int n = 0; n < 4; ++n)
                    acc[i][n] = __builtin_amdgcn_mfma_f32_16x16x32_fp8_fp8(bv[n], af[i], acc[i][n], 0, 0, 0);
            __builtin_amdgcn_s_setprio(0);
            __builtin_amdgcn_sched_barrier(0);
            readA(sb, 0, 1, af);
            if (more) stageUnit(nb, 1, 0, ktB);
            __builtin_amdgcn_sched_barrier(0);
            __builtin_amdgcn_s_setprio(1);
            #pragma unroll
            for (int i = 0; i < 4; ++i)
                #pragma unroll
                for (int n = 0; n < 4; ++n)
                    acc[4 + i][n] = __builtin_amdgcn_mfma_f32_16x16x32_fp8_fp8(bv[n], af[i], acc[4 + i][n], 0, 0, 0);
            __builtin_amdgcn_s_setprio(0);
            __builtin_amdgcn_sched_barrier(0);
        }

        // ---- k-half 1 ----
        if (more) { asm volatile("s_waitcnt vmcnt(2)" ::: "memory"); }
        else      { asm volatile("s_waitcnt vmcnt(0)" ::: "memory"); }
        __builtin_amdgcn_sched_barrier(0);
        __builtin_amdgcn_s_barrier();
        __builtin_amdgcn_sched_barrier(0);
        {
            i64 bv[4], af[4];
            readB(sb, 1, bv);
            readA(sb, 1, 0, af);
            if (more) stageUnit(nb, 0, 1, ktB);
            __builtin_amdgcn_sched_barrier(0);
            __builtin_amdgcn_s_setprio(1);
            #pragma unroll
            for (int i = 0; i < 4; ++i)
                #pragma unroll
                for (int n = 0; n < 4; ++n)
                    acc[i][n] = __builtin_amdgcn_mfma_f32_16x16x32_fp8_fp8(bv[n], af[i], acc[i][n], 0, 0, 0);
            __builtin_amdgcn_s_setprio(0);
            __builtin_amdgcn_sched_barrier(0);
            readA(sb, 1, 1, af);
            if (more) stageUnit(nb, 1, 1, ktB);
            __builtin_amdgcn_sched_barrier(0);
            __builtin_amdgcn_s_setprio(1);
            #pragma unroll
            for (int i = 0; i < 4; ++i)
                #pragma unroll
                for (int n = 0; n < 4; ++n)
                    acc[4 + i][n] = __builtin_amdgcn_mfma_f32_16x16x32_fp8_fp8(bv[n], af[i], acc[4 + i][n], 0, 0, 0);
            __builtin_amdgcn_s_setprio(0);
            __builtin_amdgcn_sched_barrier(0);
        }
    }

    // transposed D layout: lane holds row = r0+wr*128+m*16+lane15,
    // cols cb..cb+3 with cb = c0+wcol*64+n*16+q*4
    bool vld[4], svld[4]; int cb[4];
    #pragma unroll
    for (int n = 0; n < 4; ++n) {
        cb[n] = c0 + wcol * 64 + n * 16 + q * 4;
        vld[n] = (cb[n] < NTOT);
        svld[n] = vld[n] && (cb[n] >= NCAT);
        if (vld[n]) {
            float b0 = bias[cb[n]], b1 = bias[cb[n] + 1], b2 = bias[cb[n] + 2], b3 = bias[cb[n] + 3];
            #pragma unroll
            for (int m = 0; m < 8; ++m) {
                acc[m][n][0] += b0; acc[m][n][1] += b1;
                acc[m][n][2] += b2; acc[m][n][3] += b3;
            }
        }
    }

    if (by >= 10) {   // softmax partials for the l5 region
        float* fmx = (float*)sABq;           // [256][4] row-max per wcol
        float* fsm = fmx + 1024;             // [256][4] row-sumexp per wcol
        float bm[8];
        #pragma unroll
        for (int m = 0; m < 8; ++m) {
            float v = -1e30f;
            #pragma unroll
            for (int n = 0; n < 4; ++n)
                if (svld[n]) {
                    #pragma unroll
                    for (int j = 0; j < 4; ++j) v = fmaxf(v, acc[m][n][j]);
                }
            v = fmaxf(v, __shfl_xor(v, 16));
            v = fmaxf(v, __shfl_xor(v, 32));
            bm[m] = v;
        }
        __syncthreads();
        if (lane < 16) {
            #pragma unroll
            for (int m = 0; m < 8; ++m)
                fmx[(wr * 128 + m * 16 + lane15) * 4 + wcol] = bm[m];
        }
        __syncthreads();
        #pragma unroll
        for (int m = 0; m < 8; ++m) {
            int row = wr * 128 + m * 16 + lane15;
            bm[m] = fmaxf(fmaxf(fmx[row * 4], fmx[row * 4 + 1]),
                          fmaxf(fmx[row * 4 + 2], fmx[row * 4 + 3]));
        }
        float sm[8];
        #pragma unroll
        for (int m = 0; m < 8; ++m) {
            float s = 0.f;
            #pragma unroll
            for (int n = 0; n < 4; ++n)
                if (svld[n]) {
                    #pragma unroll
                    for (int j = 0; j < 4; ++j) s += __expf(acc[m][n][j] - bm[m]);
                }
            s += __shfl_xor(s, 16);
            s += __shfl_xor(s, 32);
            sm[m] = s;
        }
        if (lane < 16) {
            #pragma unroll
            for (int m = 0; m < 8; ++m)
                fsm[(wr * 128 + m * 16 + lane15) * 4 + wcol] = sm[m];
        }
        __syncthreads();
        if (t < 256) {
            float m4 = fmaxf(fmaxf(fmx[t * 4], fmx[t * 4 + 1]), fmaxf(fmx[t * 4 + 2], fmx[t * 4 + 3]));
            float s4 = fsm[t * 4] + fsm[t * 4 + 1] + fsm[t * 4 + 2] + fsm[t * 4 + 3];
            size_t idx = (size_t)(r0 + t) * NCT + (by - 10);
            pmax[idx] = m4;
            psum[idx] = s4;
        }
    }

    // store: both regions fp8 as HW-packed uint (4 cols x 1B)
    #pragma unroll
    for (int m = 0; m < 8; ++m) {
        int row = r0 + wr * 128 + m * 16 + lane15;
        #pragma unroll
        for (int n = 0; n < 4; ++n) {
            if (vld[n]) {
                unsigned int v = pack4_fp8(acc[m][n][0], acc[m][n][1], acc[m][n][2], acc[m][n][3]);
                u8* dst = (cb[n] < NCAT)
                    ? &pcat[(size_t)row * LDP + cb[n]]
                    : &l5f8[(size_t)row * NC5 + (cb[n] - NCAT)];
                *reinterpret_cast<unsigned int*>(dst) = v;
            }
        }
    }
}

// ---------------- fused LSE + CE + probabilities + all JSDs (256-thread block per row) ----------------

__global__ __launch_bounds__(256) void probs_all(const u8* __restrict__ l5f8, float* __restrict__ out,
                                                 const u8* __restrict__ pcat,
                                                 const float* __restrict__ pmax, const float* __restrict__ psum,
                                                 const int* __restrict__ tgt,
                                                 float* __restrict__ cerow,
                                                 float* __restrict__ j12, float* __restrict__ j23,
                                                 float* __restrict__ j34, float* __restrict__ j45) {
    __shared__ u16 P5[NC5];
    __shared__ float PC[LDP];
    __shared__ float sh[4];
    __shared__ float shls;
    int b = blockIdx.x, t = threadIdx.x;
    float* orow = out + (size_t)b * NC5;
    const u8* lrow = l5f8 + (size_t)b * NC5;
    const u8* prow = pcat + (size_t)b * LDP;

    // wave 0: reduce the per-coltile partials into the row LSE
    if (t < 64) {
        float pm = (t < NCT) ? pmax[(size_t)b * NCT + t] : -1e30f;
        float ps = (t < NCT) ? psum[(size_t)b * NCT + t] : 0.f;
        float gm = waveReduceMax(pm);
        float s = waveReduceSum(ps * __expf(pm - gm));
        if (t == 0) {
            float ls = gm + __logf(s);
            shls = ls;
            int tg = tgt[b];
            cerow[b] = -(fp8_1(lrow[tg]) - ls);
        }
    }
    // stage pcat row (fp8) into LDS as f32: 328 items of 8 (PC sized LDP, no guard)
    for (int c = t; c < LDP / 8; c += 256) {
        uint2 raw = ((const uint2*)prow)[c];
        f32x4 a = unpack4_fp8(raw.x);
        f32x4 bb = unpack4_fp8(raw.y);
        int base = c * 8;
        #pragma unroll
        for (int k = 0; k < 4; ++k) PC[base + k] = a[k];
        #pragma unroll
        for (int k = 0; k < 4; ++k) PC[base + 4 + k] = bb[k];
    }
    __syncthreads();
    float ls = shls;

    // l5 row: 1250 items of 8 fp8 (uint2 cached load); two f32x4 NT stores
    for (int c = t; c < NC5 / 8; c += 256) {
        uint2 raw = ((const uint2*)lrow)[c];
        f32x4 l0 = unpack4_fp8(raw.x);
        f32x4 l1 = unpack4_fp8(raw.y);
        f32x4 o0, o1;
        #pragma unroll
        for (int k = 0; k < 4; ++k) o0[k] = __expf(l0[k] - ls);
        #pragma unroll
        for (int k = 0; k < 4; ++k) o1[k] = __expf(l1[k] - ls);
        __builtin_nontemporal_store(o0, &((f32x4*)orow)[c * 2]);
        __builtin_nontemporal_store(o1, &((f32x4*)orow)[c * 2 + 1]);
        union { u16 u[8]; uint4 v; } pk;
        #pragma unroll
        for (int k = 0; k < 4; ++k) pk.u[k] = f2bf(o0[k]);
        #pragma unroll
        for (int k = 0; k < 4; ++k) pk.u[4 + k] = f2bf(o1[k]);
        ((uint4*)P5)[c] = pk.v;
    }
    __syncthreads();

    auto softmax_seg = [&](int off, int C) {
        float m = -1e30f;
        for (int c = t; c < C; c += 256) m = fmaxf(m, PC[off + c]);
        m = blockReduceMax(m, sh);
        float s = 0.f;
        for (int c = t; c < C; c += 256) { float e = __expf(PC[off + c] - m); PC[off + c] = e; s += e; }
        s = blockReduceSum(s, sh);
        float inv = 1.0f / s;
        for (int c = t; c < C; c += 256) PC[off + c] *= inv;
    };
    softmax_seg(0, NC1);
    softmax_seg(20, NC2);
    softmax_seg(120, NC3);
    softmax_seg(620, NC4);
    __syncthreads();

    {   // jsd45: agg p5 (fan 5) vs p4
        float klpm = 0.f, klqm = 0.f;
        for (int g = t; g < NC4; g += 256) {
            float qv = 0.f;
            #pragma unroll
            for (int f = 0; f < 5; ++f) qv += bfu(P5[5 * g + f]);
            float pp = PC[620 + g];
            float mm = 0.5f * (qv + pp);
            float lm = __logf(mm + 1e-8f);
            klpm += qv * (__logf(qv + 1e-8f) - lm);
            klqm += pp * (__logf(pp + 1e-8f) - lm);
        }
        float tot = blockReduceSum(0.5f * (klpm + klqm), sh);
        if (t == 0) j45[b] = tot;
    }
    auto jsd_seg = [&](int childOff, int fan, int parentOff, int nPar, float* dst) {
        float klpm = 0.f, klqm = 0.f;
        for (int g = t; g < nPar; g += 256) {
            float qv = 0.f;
            for (int f = 0; f < fan; ++f) qv += PC[childOff + g * fan + f];
            float pp = PC[parentOff + g];
            float mm = 0.5f * (qv + pp);
            float lm = __logf(mm + 1e-8f);
            klpm += qv * (__logf(qv + 1e-8f) - lm);
            klqm += pp * (__logf(pp + 1e-8f) - lm);
        }
        float tot = blockReduceSum(0.5f * (klpm + klqm), sh);
        if (t == 0) dst[b] = tot;
    };
    jsd_seg(620, 4, 120, NC3, j34);
    jsd_seg(120, 5, 20, NC2, j23);
    jsd_seg(20, 5, 0, NC1, j12);
}

__global__ __launch_bounds__(256) void finalize(const float* __restrict__ ce, const float* __restrict__ j45,
                                                const float* __restrict__ j34, const float* __restrict__ j23,
                                                const float* __restrict__ j12, const float* __restrict__ c45,
                                                const float* __restrict__ c34, const float* __restrict__ c23,
                                                const float* __restrict__ c12, float* __restrict__ lossOut) {
    __shared__ float sh[4];
    auto meanArr = [&](const float* a, int n) {
        float s = 0.f;
        for (int i = threadIdx.x; i < n; i += 256) s += a[i];
        s = blockReduceSum(s, sh);
        return s / n;
    };
    float loss = meanArr(ce, BATCH);
    loss += meanArr(j45, BATCH) + meanArr(j34, BATCH) + meanArr(j23, BATCH) + meanArr(j12, BATCH);
    loss -= meanArr(c45, NC4) + meanArr(c34, NC3) + meanArr(c23, NC2) + meanArr(c12, NC1);
    if (threadIdx.x == 0) *lossOut = loss;
}

// ---------------- launch ----------------

extern "C" void kernel_launch(void* const* d_in, const int* in_sizes, int n_in,
                              void* d_out, int out_size, void* d_ws, size_t ws_size,
                              hipStream_t stream) {
    const float* x  = (const float*)d_in[0];
    const int*   tg = (const int*)d_in[1];
    const float* W1 = (const float*)d_in[2];  const float* b1 = (const float*)d_in[3];
    const float* W2 = (const float*)d_in[4];  const float* b2 = (const float*)d_in[5];
    const float* W3 = (const float*)d_in[6];  const float* b3 = (const float*)d_in[7];
    const float* W4 = (const float*)d_in[8];  const float* b4 = (const float*)d_in[9];
    const float* W5 = (const float*)d_in[10]; const float* b5 = (const float*)d_in[11];
    float* out = (float*)d_out;

    char* ws = (char*)d_ws;
    size_t off = 0;
    auto alloc = [&](size_t bytes) { void* p = ws + off; off = (off + bytes + 255) & ~(size_t)255; return p; };
    u8*    xb8     = (u8*)alloc((size_t)BATCH * FEAT);
    u8*    wb8     = (u8*)alloc((size_t)NTOT * FEAT);
    float* biascat = (float*)alloc((size_t)NTOT * 4);
    u8*    pcat    = (u8*)alloc((size_t)BATCH * LDP);
    u8*    l5f8    = (u8*)alloc((size_t)BATCH * NC5);
    float* pmax    = (float*)alloc((size_t)BATCH * NCT * 4);
    float* psum    = (float*)alloc((size_t)BATCH * NCT * 4);
    float* cerow   = (float*)alloc((size_t)BATCH * 4);
    float* j45     = (float*)alloc((size_t)BATCH * 4);
    float* j34     = (float*)alloc((size_t)BATCH * 4);
    float* j23     = (float*)alloc((size_t)BATCH * 4);
    float* j12     = (float*)alloc((size_t)BATCH * 4);
    float* c45     = (float*)alloc((size_t)NC4 * 4);
    float* c34     = (float*)alloc((size_t)NC3 * 4);
    float* c23     = (float*)alloc((size_t)NC2 * 4);
    float* c12     = (float*)alloc((size_t)NC1 * 4);

    prep<<<WN_BLOCKS + CAST_BLOCKS + WCOS_BLOCKS, 256, 0, stream>>>(
        x, xb8, W1, b1, W2, b2, W3, b3, W4, b4, W5, b5, wb8, biascat, c45, c34, c23, c12);

    gemm_all<<<dim3(BATCH / BM, (NTOT + BN - 1) / BN), 512, 0, stream>>>(
        xb8, wb8, biascat, pcat, l5f8, pmax, psum);

    probs_all<<<BATCH, 256, 0, stream>>>(l5f8, out, pcat, pmax, psum, tg, cerow,
                                         j12, j23, j34, j45);

    finalize<<<1, 256, 0, stream>>>(cerow, j45, j34, j23, j12, c45, c34, c23, c12,
                                    out + (size_t)BATCH * NC5);
}

// Round 20
// 342.714 us; speedup vs baseline: 1.0555x; 1.0038x over previous
//
#include <hip/hip_runtime.h>
#include <hip/hip_bf16.h>
#include <stdint.h>

typedef unsigned short u16;
typedef unsigned char u8;
typedef long i64;
typedef float f32x2 __attribute__((ext_vector_type(2)));
typedef float f32x4 __attribute__((ext_vector_type(4)));
typedef unsigned int u32x4 __attribute__((ext_vector_type(4)));

#define FEAT 512
#define BATCH 8192
#define NC1 20
#define NC2 100
#define NC3 500
#define NC4 2000
#define NC5 10000
#define NCAT 2620
#define LDP 2624          // padded leading dim for pcat (fp8 bytes, 16B-clean)
#define NTOT 12620
#define NCT 40            // l5 col tiles (by = 10..49)
#define WN_BLOCKS 3155    // ceil(12620 / 4) wnorm blocks (4 rows x 64 lanes)
#define CAST_BLOCKS 2048  // 8192*512/8/256
#define NGRP 2620         // cosine groups total
#define WCOS_BLOCKS 655   // ceil(2620 / 4)

__device__ inline u16 f2bf(float f) {
    unsigned int u = __builtin_bit_cast(unsigned int, f);
    unsigned int r = (u + 0x7FFFu + ((u >> 16) & 1u)) >> 16;
    return (u16)r;
}
__device__ inline float bfu(u16 u) {
    return __builtin_bit_cast(float, (unsigned int)u << 16);
}
// HW fp8 e4m3 (OCP on gfx950) pack/unpack
__device__ inline unsigned int pack4_fp8(float a0, float a1, float a2, float a3) {
    int v = 0;
    v = __builtin_amdgcn_cvt_pk_fp8_f32(a0, a1, v, false);
    v = __builtin_amdgcn_cvt_pk_fp8_f32(a2, a3, v, true);
    return (unsigned int)v;
}
__device__ inline f32x4 unpack4_fp8(unsigned int v) {
    f32x2 lo = __builtin_amdgcn_cvt_pk_f32_fp8((int)v, false);
    f32x2 hi = __builtin_amdgcn_cvt_pk_f32_fp8((int)v, true);
    f32x4 o; o[0] = lo[0]; o[1] = lo[1]; o[2] = hi[0]; o[3] = hi[1];
    return o;
}
__device__ inline float fp8_1(u8 u) {
    return __builtin_amdgcn_cvt_f32_fp8((int)u, 0);
}

__device__ inline float waveReduceSum(float v) {
    #pragma unroll
    for (int off = 32; off > 0; off >>= 1) v += __shfl_xor(v, off);
    return v;
}
__device__ inline float waveReduceMax(float v) {
    #pragma unroll
    for (int off = 32; off > 0; off >>= 1) v = fmaxf(v, __shfl_xor(v, off));
    return v;
}
// 256-thread blocks
__device__ inline float blockReduceSum(float v, float* sh) {
    int t = threadIdx.x;
    v = waveReduceSum(v);
    __syncthreads();
    if ((t & 63) == 0) sh[t >> 6] = v;
    __syncthreads();
    return sh[0] + sh[1] + sh[2] + sh[3];
}

__device__ inline void gload16(const void* g, void* l) {
    __builtin_amdgcn_global_load_lds((const __attribute__((address_space(1))) void*)g,
                                     (__attribute__((address_space(3))) void*)l, 16, 0, 0);
}

// ---------------- prep: cast x/W to fp8, l2-normalize weights, wcos terms ----------------

__global__ __launch_bounds__(256) void prep(const float* __restrict__ x, u8* __restrict__ xb8,
                                            const float* __restrict__ W1, const float* __restrict__ b1,
                                            const float* __restrict__ W2, const float* __restrict__ b2,
                                            const float* __restrict__ W3, const float* __restrict__ b3,
                                            const float* __restrict__ W4, const float* __restrict__ b4,
                                            const float* __restrict__ W5, const float* __restrict__ b5,
                                            u8* __restrict__ wb8, float* __restrict__ biascat,
                                            float* __restrict__ c45, float* __restrict__ c34,
                                            float* __restrict__ c23, float* __restrict__ c12) {
    int bid = blockIdx.x;
    if (bid < WN_BLOCKS) {
        int r = bid * 4 + (threadIdx.x >> 6);
        if (r >= NTOT) return;
        int t = threadIdx.x & 63;
        const float* W; const float* b; int lr;
        if      (r < 20)   { W = W1; b = b1; lr = r; }
        else if (r < 120)  { W = W2; b = b2; lr = r - 20; }
        else if (r < 620)  { W = W3; b = b3; lr = r - 120; }
        else if (r < 2620) { W = W4; b = b4; lr = r - 620; }
        else               { W = W5; b = b5; lr = r - 2620; }
        const float* p = W + (size_t)lr * FEAT + t * 8;
        float v[8]; float ss = 0.f;
        #pragma unroll
        for (int j = 0; j < 8; ++j) { v[j] = p[j]; ss += v[j] * v[j]; }
        ss = waveReduceSum(ss);
        float inv = 1.0f / fmaxf(sqrtf(ss), 1e-12f);
        uint2 o;
        o.x = pack4_fp8(v[0] * inv, v[1] * inv, v[2] * inv, v[3] * inv);
        o.y = pack4_fp8(v[4] * inv, v[5] * inv, v[6] * inv, v[7] * inv);
        *reinterpret_cast<uint2*>(wb8 + (size_t)r * FEAT + t * 8) = o;
        if (t == 0) biascat[r] = b[lr];
    } else if (bid < WN_BLOCKS + CAST_BLOCKS) {
        int i = (bid - WN_BLOCKS) * 256 + threadIdx.x;
        const float* p = x + (size_t)i * 8;
        uint2 o;
        o.x = pack4_fp8(p[0], p[1], p[2], p[3]);
        o.y = pack4_fp8(p[4], p[5], p[6], p[7]);
        *reinterpret_cast<uint2*>(xb8 + (size_t)i * 8) = o;
    } else {
        // weight-cosine terms: one wave per group, 4 groups per block (raw f32 W)
        int g = (bid - WN_BLOCKS - CAST_BLOCKS) * 4 + (threadIdx.x >> 6);
        if (g >= NGRP) return;
        int t = threadIdx.x & 63;
        const float* Wp; const float* Wc; int fan, j; float* dst;
        if      (g < 2000) { Wp = W4; Wc = W5; fan = 5; dst = c45; j = g; }
        else if (g < 2500) { Wp = W3; Wc = W4; fan = 4; dst = c34; j = g - 2000; }
        else if (g < 2600) { Wp = W2; Wc = W3; fan = 5; dst = c23; j = g - 2500; }
        else               { Wp = W1; Wc = W2; fan = 5; dst = c12; j = g - 2600; }

        float hat[8] = {0, 0, 0, 0, 0, 0, 0, 0};
        for (int c = 0; c < fan; ++c) {
            const float* cr = Wc + ((size_t)(j * fan + c)) * FEAT + t * 8;
            float v[8]; float ss = 0.f;
            #pragma unroll
            for (int i = 0; i < 8; ++i) { v[i] = cr[i]; ss += v[i] * v[i]; }
            ss = waveReduceSum(ss);
            float inv = 1.0f / fmaxf(sqrtf(ss), 1e-12f);
            #pragma unroll
            for (int i = 0; i < 8; ++i) hat[i] += v[i] * inv;
        }
        float hs = 0.f;
        #pragma unroll
        for (int i = 0; i < 8; ++i) hs += hat[i] * hat[i];
        hs = waveReduceSum(hs);
        float hinv = 1.0f / fmaxf(sqrtf(hs), 1e-12f);
        const float* pr = Wp + (size_t)j * FEAT + t * 8;
        float ps = 0.f, dot = 0.f;
        #pragma unroll
        for (int i = 0; i < 8; ++i) { float pv = pr[i]; ps += pv * pv; dot += pv * hat[i]; }
        ps = waveReduceSum(ps);
        dot = waveReduceSum(dot);
        if (t == 0) dst[j] = dot * hinv / fmaxf(sqrtf(ps), 1e-12f);
    }
}

// ---------------- fp8 GEMM over all 12620 columns (unchanged from R19) ----------------

#define BM 256
#define BN 256
#define BK 64
#define KITERS (FEAT / BK)

__global__ __launch_bounds__(512, 2) void gemm_all(const u8* __restrict__ A, const u8* __restrict__ Bw,
                                                   const float* __restrict__ bias,
                                                   u8* __restrict__ pcat, u8* __restrict__ l5f8,
                                                   float* __restrict__ pmax, float* __restrict__ psum) {
    __shared__ uint4 sABq[2][2048];            // 2 x 32 KB double buffer
    const int t = threadIdx.x;
    const int lane = t & 63, wid = t >> 6;
    const int lane15 = lane & 15, q = lane >> 4;
    const int wr = wid >> 2, wcol = wid & 3;

    // XCD-aware bijective swizzle (nwg = 32*50 = 1600, %8 == 0)
    int nwg = gridDim.x * gridDim.y;
    int lid = blockIdx.y * gridDim.x + blockIdx.x;
    int cpx = nwg >> 3;
    int swz = (lid & 7) * cpx + (lid >> 3);
    int bx = swz % gridDim.x, by = swz / gridDim.x;
    const int r0 = bx * BM, c0 = by * BN;

    f32x4 acc[8][4];
    #pragma unroll
    for (int m = 0; m < 8; ++m)
        #pragma unroll
        for (int n = 0; n < 4; ++n) acc[m][n] = f32x4{0.f, 0.f, 0.f, 0.f};

    // stage one unit (region, kh): 512 chunks of 16B, 1 per thread, LINEAR dest
    auto stageUnit = [&](char* nb, int region, int kh, int ktB) {
        int row = t & 255, p = t >> 8;
        int srck = ktB + kh * 32 + p * 16;
        const u8* g;
        if (region == 0) {
            g = A + (size_t)(r0 + row) * FEAT + srck;
        } else {
            int br = c0 + row; if (br >= NTOT) br = NTOT - 1;
            g = Bw + (size_t)br * FEAT + srck;
        }
        gload16(g, nb + region * 16384 + kh * 8192 + (size_t)t * 16);
    };

    // fragment reads: 8 fp8 (b64) at row r; k offset q*8 = (q>>1)*16 + (q&1)*8
    auto readA = [&](char* sb, int ks, int mh, i64* af) {
        #pragma unroll
        for (int i = 0; i < 4; ++i) {
            int row = wr * 128 + (mh * 4 + i) * 16 + lane15;
            af[i] = *reinterpret_cast<const i64*>(sb + ks * 8192 + (q >> 1) * 4096 +
                                                  row * 16 + (q & 1) * 8);
        }
    };
    auto readB = [&](char* sb, int ks, i64* bv) {
        #pragma unroll
        for (int n = 0; n < 4; ++n) {
            int row = wcol * 64 + n * 16 + lane15;
            bv[n] = *reinterpret_cast<const i64*>(sb + 16384 + ks * 8192 + (q >> 1) * 4096 +
                                                  row * 16 + (q & 1) * 8);
        }
    };

    // prologue: tile 0's four units, oldest-first {A-k0, B-k0, A-k1, B-k1}
    {
        char* nb = (char*)sABq[0];
        stageUnit(nb, 0, 0, 0);
        stageUnit(nb, 1, 0, 0);
        stageUnit(nb, 0, 1, 0);
        stageUnit(nb, 1, 1, 0);
    }

    for (int T = 0; T < KITERS; ++T) {
        char* sb = (char*)sABq[T & 1];
        char* nb = (char*)sABq[(T + 1) & 1];
        const bool more = (T + 1 < KITERS);
        const int ktB = (T + 1) * BK;

        // ---- k-half 0 ----
        asm volatile("s_waitcnt vmcnt(2)" ::: "memory");
        __builtin_amdgcn_sched_barrier(0);
        __builtin_amdgcn_s_barrier();
        __builtin_amdgcn_sched_barrier(0);
        {
            i64 bv[4], af[4];
            readB(sb, 0, bv);
            readA(sb, 0, 0, af);
            if (more) stageUnit(nb, 0, 0, ktB);
            __builtin_amdgcn_sched_barrier(0);
            __builtin_amdgcn_s_setprio(1);
            #pragma unroll
            for (int i = 0; i < 4; ++i)
                #pragma unroll
                for (int n = 0; n < 4; ++n)
                    acc[i][n] = __builtin_amdgcn_mfma_f32_16x16x32_fp8_fp8(bv[n], af[i], acc[i][n], 0, 0, 0);
            __builtin_amdgcn_s_setprio(0);
            __builtin_amdgcn_sched_barrier(0);
            readA(sb, 0, 1, af);
            if (more) stageUnit(nb, 1, 0, ktB);
            __builtin_amdgcn_sched_barrier(0);
            __builtin_amdgcn_s_setprio(1);
            #pragma unroll
            for (int i = 0; i < 4; ++i)
                #pragma unroll
                for (int n = 0; n < 4; ++n)
                    acc[4 + i][n] = __builtin_amdgcn_mfma_f32_16x16x32_fp8_fp8(bv[n], af[i], acc[4 + i][n], 0, 0, 0);
            __builtin_amdgcn_s_setprio(0);
            __builtin_amdgcn_sched_barrier(0);
        }

        // ---- k-half 1 ----
        if (more) { asm volatile("s_waitcnt vmcnt(2)" ::: "memory"); }
        else      { asm volatile("s_waitcnt vmcnt(0)" ::: "memory"); }
        __builtin_amdgcn_sched_barrier(0);
        __builtin_amdgcn_s_barrier();
        __builtin_amdgcn_sched_barrier(0);
        {
            i64 bv[4], af[4];
            readB(sb, 1, bv);
            readA(sb, 1, 0, af);
            if (more) stageUnit(nb, 0, 1, ktB);
            __builtin_amdgcn_sched_barrier(0);
            __builtin_amdgcn_s_setprio(1);
            #pragma unroll
            for (int i = 0; i < 4; ++i)
                #pragma unroll
                for (int n = 0; n < 4; ++n)
                    acc[i][n] = __builtin_amdgcn_mfma_f32_16x16x32_fp8_fp8(bv[n], af[i], acc[i][n], 0, 0, 0);
            __builtin_amdgcn_s_setprio(0);
            __builtin_amdgcn_sched_barrier(0);
            readA(sb, 1, 1, af);
            if (more) stageUnit(nb, 1, 1, ktB);
            __builtin_amdgcn_sched_barrier(0);
            __builtin_amdgcn_s_setprio(1);
            #pragma unroll
            for (int i = 0; i < 4; ++i)
                #pragma unroll
                for (int n = 0; n < 4; ++n)
                    acc[4 + i][n] = __builtin_amdgcn_mfma_f32_16x16x32_fp8_fp8(bv[n], af[i], acc[4 + i][n], 0, 0, 0);
            __builtin_amdgcn_s_setprio(0);
            __builtin_amdgcn_sched_barrier(0);
        }
    }

    // transposed D layout: lane holds row = r0+wr*128+m*16+lane15,
    // cols cb..cb+3 with cb = c0+wcol*64+n*16+q*4
    bool vld[4], svld[4]; int cb[4];
    #pragma unroll
    for (int n = 0; n < 4; ++n) {
        cb[n] = c0 + wcol * 64 + n * 16 + q * 4;
        vld[n] = (cb[n] < NTOT);
        svld[n] = vld[n] && (cb[n] >= NCAT);
        if (vld[n]) {
            float b0 = bias[cb[n]], b1 = bias[cb[n] + 1], b2 = bias[cb[n] + 2], b3 = bias[cb[n] + 3];
            #pragma unroll
            for (int m = 0; m < 8; ++m) {
                acc[m][n][0] += b0; acc[m][n][1] += b1;
                acc[m][n][2] += b2; acc[m][n][3] += b3;
            }
        }
    }

    if (by >= 10) {   // softmax partials for the l5 region
        float* fmx = (float*)sABq;           // [256][4] row-max per wcol
        float* fsm = fmx + 1024;             // [256][4] row-sumexp per wcol
        float bm[8];
        #pragma unroll
        for (int m = 0; m < 8; ++m) {
            float v = -1e30f;
            #pragma unroll
            for (int n = 0; n < 4; ++n)
                if (svld[n]) {
                    #pragma unroll
                    for (int j = 0; j < 4; ++j) v = fmaxf(v, acc[m][n][j]);
                }
            v = fmaxf(v, __shfl_xor(v, 16));
            v = fmaxf(v, __shfl_xor(v, 32));
            bm[m] = v;
        }
        __syncthreads();
        if (lane < 16) {
            #pragma unroll
            for (int m = 0; m < 8; ++m)
                fmx[(wr * 128 + m * 16 + lane15) * 4 + wcol] = bm[m];
        }
        __syncthreads();
        #pragma unroll
        for (int m = 0; m < 8; ++m) {
            int row = wr * 128 + m * 16 + lane15;
            bm[m] = fmaxf(fmaxf(fmx[row * 4], fmx[row * 4 + 1]),
                          fmaxf(fmx[row * 4 + 2], fmx[row * 4 + 3]));
        }
        float sm[8];
        #pragma unroll
        for (int m = 0; m < 8; ++m) {
            float s = 0.f;
            #pragma unroll
            for (int n = 0; n < 4; ++n)
                if (svld[n]) {
                    #pragma unroll
                    for (int j = 0; j < 4; ++j) s += __expf(acc[m][n][j] - bm[m]);
                }
            s += __shfl_xor(s, 16);
            s += __shfl_xor(s, 32);
            sm[m] = s;
        }
        if (lane < 16) {
            #pragma unroll
            for (int m = 0; m < 8; ++m)
                fsm[(wr * 128 + m * 16 + lane15) * 4 + wcol] = sm[m];
        }
        __syncthreads();
        if (t < 256) {
            float m4 = fmaxf(fmaxf(fmx[t * 4], fmx[t * 4 + 1]), fmaxf(fmx[t * 4 + 2], fmx[t * 4 + 3]));
            float s4 = fsm[t * 4] + fsm[t * 4 + 1] + fsm[t * 4 + 2] + fsm[t * 4 + 3];
            size_t idx = (size_t)(r0 + t) * NCT + (by - 10);
            pmax[idx] = m4;
            psum[idx] = s4;
        }
    }

    // store: both regions fp8 as HW-packed uint (4 cols x 1B)
    #pragma unroll
    for (int m = 0; m < 8; ++m) {
        int row = r0 + wr * 128 + m * 16 + lane15;
        #pragma unroll
        for (int n = 0; n < 4; ++n) {
            if (vld[n]) {
                unsigned int v = pack4_fp8(acc[m][n][0], acc[m][n][1], acc[m][n][2], acc[m][n][3]);
                u8* dst = (cb[n] < NCAT)
                    ? &pcat[(size_t)row * LDP + cb[n]]
                    : &l5f8[(size_t)row * NC5 + (cb[n] - NCAT)];
                *reinterpret_cast<unsigned int*>(dst) = v;
            }
        }
    }
}

// ---------------- fused LSE + CE + probabilities + all JSDs ----------------
// 256-thread block per row; softmax segments and JSD terms distributed
// ACROSS WAVES (wave-reduce only, 3 block barriers total).

__global__ __launch_bounds__(256) void probs_all(const u8* __restrict__ l5f8, float* __restrict__ out,
                                                 const u8* __restrict__ pcat,
                                                 const float* __restrict__ pmax, const float* __restrict__ psum,
                                                 const int* __restrict__ tgt,
                                                 float* __restrict__ cerow,
                                                 float* __restrict__ j12, float* __restrict__ j23,
                                                 float* __restrict__ j34, float* __restrict__ j45) {
    __shared__ u16 P5[NC5];
    __shared__ float PC[LDP];
    __shared__ float sh[4];
    __shared__ float shls;
    int b = blockIdx.x, t = threadIdx.x;
    int w = t >> 6, lane = t & 63;
    float* orow = out + (size_t)b * NC5;
    const u8* lrow = l5f8 + (size_t)b * NC5;
    const u8* prow = pcat + (size_t)b * LDP;

    // wave 0: reduce the per-coltile partials into the row LSE
    if (t < 64) {
        float pm = (t < NCT) ? pmax[(size_t)b * NCT + t] : -1e30f;
        float ps = (t < NCT) ? psum[(size_t)b * NCT + t] : 0.f;
        float gm = waveReduceMax(pm);
        float s = waveReduceSum(ps * __expf(pm - gm));
        if (t == 0) {
            float ls = gm + __logf(s);
            shls = ls;
            int tg = tgt[b];
            cerow[b] = -(fp8_1(lrow[tg]) - ls);
        }
    }
    // stage pcat row (fp8) into LDS as f32: 328 items of 8
    for (int c = t; c < LDP / 8; c += 256) {
        uint2 raw = ((const uint2*)prow)[c];
        f32x4 a = unpack4_fp8(raw.x);
        f32x4 bb = unpack4_fp8(raw.y);
        int base = c * 8;
        #pragma unroll
        for (int k = 0; k < 4; ++k) PC[base + k] = a[k];
        #pragma unroll
        for (int k = 0; k < 4; ++k) PC[base + 4 + k] = bb[k];
    }
    __syncthreads();
    float ls = shls;

    // l5 row: 1250 items of 8 fp8 (uint2 cached load); two f32x4 NT stores
    for (int c = t; c < NC5 / 8; c += 256) {
        uint2 raw = ((const uint2*)lrow)[c];
        f32x4 l0 = unpack4_fp8(raw.x);
        f32x4 l1 = unpack4_fp8(raw.y);
        f32x4 o0, o1;
        #pragma unroll
        for (int k = 0; k < 4; ++k) o0[k] = __expf(l0[k] - ls);
        #pragma unroll
        for (int k = 0; k < 4; ++k) o1[k] = __expf(l1[k] - ls);
        __builtin_nontemporal_store(o0, &((f32x4*)orow)[c * 2]);
        __builtin_nontemporal_store(o1, &((f32x4*)orow)[c * 2 + 1]);
        union { u16 u[8]; uint4 v; } pk;
        #pragma unroll
        for (int k = 0; k < 4; ++k) pk.u[k] = f2bf(o0[k]);
        #pragma unroll
        for (int k = 0; k < 4; ++k) pk.u[4 + k] = f2bf(o1[k]);
        ((uint4*)P5)[c] = pk.v;
    }
    __syncthreads();

    // ---- wave-parallel softmax over PC segments (no block barriers inside) ----
    // wave 0: {0,20} then {20,100}; wave 1: {120,500}; waves 2,3: {620,2000}
    // (waves 2 and 3 duplicate identical work/writes -> race-free).
    auto wave_softmax = [&](int off, int C) {
        float m = -1e30f;
        for (int c = lane; c < C; c += 64) m = fmaxf(m, PC[off + c]);
        m = waveReduceMax(m);
        float s = 0.f;
        for (int c = lane; c < C; c += 64) s += __expf(PC[off + c] - m);
        s = waveReduceSum(s);
        float inv = 1.0f / s;
        for (int c = lane; c < C; c += 64) PC[off + c] = __expf(PC[off + c] - m) * inv;
    };
    if (w == 0) { wave_softmax(0, NC1); wave_softmax(20, NC2); }
    else if (w == 1) { wave_softmax(120, NC3); }
    else { wave_softmax(620, NC4); }
    __syncthreads();

    // ---- wave-parallel JSD terms ----
    // wave 0: j12 + j23; wave 1: j34; wave 2: j45 lower half; wave 3: upper half.
    auto jsd_wave = [&](int childOff, int fan, int parentOff, int gLo, int gHi) {
        float klpm = 0.f, klqm = 0.f;
        for (int g = gLo + lane; g < gHi; g += 64) {
            float qv = 0.f;
            for (int f = 0; f < fan; ++f) qv += PC[childOff + g * fan + f];
            float pp = PC[parentOff + g];
            float mm = 0.5f * (qv + pp);
            float lm = __logf(mm + 1e-8f);
            klpm += qv * (__logf(qv + 1e-8f) - lm);
            klqm += pp * (__logf(pp + 1e-8f) - lm);
        }
        return waveReduceSum(0.5f * (klpm + klqm));
    };
    if (w == 0) {
        float v12 = jsd_wave(20, 5, 0, 0, NC1);
        float v23 = jsd_wave(120, 5, 20, 0, NC2);
        if (lane == 0) { j12[b] = v12; j23[b] = v23; }
    } else if (w == 1) {
        float v34 = jsd_wave(620, 4, 120, 0, NC3);
        if (lane == 0) j34[b] = v34;
    } else {
        // jsd45: agg p5 (fan 5, from bf16 P5) vs p4; waves 2/3 split halves
        int gLo = (w == 2) ? 0 : NC4 / 2;
        int gHi = (w == 2) ? NC4 / 2 : NC4;
        float klpm = 0.f, klqm = 0.f;
        for (int g = gLo + lane; g < gHi; g += 64) {
            float qv = 0.f;
            #pragma unroll
            for (int f = 0; f < 5; ++f) qv += bfu(P5[5 * g + f]);
            float pp = PC[620 + g];
            float mm = 0.5f * (qv + pp);
            float lm = __logf(mm + 1e-8f);
            klpm += qv * (__logf(qv + 1e-8f) - lm);
            klqm += pp * (__logf(pp + 1e-8f) - lm);
        }
        float part = waveReduceSum(0.5f * (klpm + klqm));
        if (lane == 0) sh[w - 2] = part;
    }
    __syncthreads();
    if (t == 0) j45[b] = sh[0] + sh[1];
}

__global__ __launch_bounds__(256) void finalize(const float* __restrict__ ce, const float* __restrict__ j45,
                                                const float* __restrict__ j34, const float* __restrict__ j23,
                                                const float* __restrict__ j12, const float* __restrict__ c45,
                                                const float* __restrict__ c34, const float* __restrict__ c23,
                                                const float* __restrict__ c12, float* __restrict__ lossOut) {
    __shared__ float sh[4];
    auto meanArr = [&](const float* a, int n) {
        float s = 0.f;
        for (int i = threadIdx.x; i < n; i += 256) s += a[i];
        s = blockReduceSum(s, sh);
        return s / n;
    };
    float loss = meanArr(ce, BATCH);
    loss += meanArr(j45, BATCH) + meanArr(j34, BATCH) + meanArr(j23, BATCH) + meanArr(j12, BATCH);
    loss -= meanArr(c45, NC4) + meanArr(c34, NC3) + meanArr(c23, NC2) + meanArr(c12, NC1);
    if (threadIdx.x == 0) *lossOut = loss;
}

// ---------------- launch ----------------

extern "C" void kernel_launch(void* const* d_in, const int* in_sizes, int n_in,
                              void* d_out, int out_size, void* d_ws, size_t ws_size,
                              hipStream_t stream) {
    const float* x  = (const float*)d_in[0];
    const int*   tg = (const int*)d_in[1];
    const float* W1 = (const float*)d_in[2];  const float* b1 = (const float*)d_in[3];
    const float* W2 = (const float*)d_in[4];  const float* b2 = (const float*)d_in[5];
    const float* W3 = (const float*)d_in[6];  const float* b3 = (const float*)d_in[7];
    const float* W4 = (const float*)d_in[8];  const float* b4 = (const float*)d_in[9];
    const float* W5 = (const float*)d_in[10]; const float* b5 = (const float*)d_in[11];
    float* out = (float*)d_out;

    char* ws = (char*)d_ws;
    size_t off = 0;
    auto alloc = [&](size_t bytes) { void* p = ws + off; off = (off + bytes + 255) & ~(size_t)255; return p; };
    u8*    xb8     = (u8*)alloc((size_t)BATCH * FEAT);
    u8*    wb8     = (u8*)alloc((size_t)NTOT * FEAT);
    float* biascat = (float*)alloc((size_t)NTOT * 4);
    u8*    pcat    = (u8*)alloc((size_t)BATCH * LDP);
    u8*    l5f8    = (u8*)alloc((size_t)BATCH * NC5);
    float* pmax    = (float*)alloc((size_t)BATCH * NCT * 4);
    float* psum    = (float*)alloc((size_t)BATCH * NCT * 4);
    float* cerow   = (float*)alloc((size_t)BATCH * 4);
    float* j45     = (float*)alloc((size_t)BATCH * 4);
    float* j34     = (float*)alloc((size_t)BATCH * 4);
    float* j23     = (float*)alloc((size_t)BATCH * 4);
    float* j12     = (float*)alloc((size_t)BATCH * 4);
    float* c45     = (float*)alloc((size_t)NC4 * 4);
    float* c34     = (float*)alloc((size_t)NC3 * 4);
    float* c23     = (float*)alloc((size_t)NC2 * 4);
    float* c12     = (float*)alloc((size_t)NC1 * 4);

    prep<<<WN_BLOCKS + CAST_BLOCKS + WCOS_BLOCKS, 256, 0, stream>>>(
        x, xb8, W1, b1, W2, b2, W3, b3, W4, b4, W5, b5, wb8, biascat, c45, c34, c23, c12);

    gemm_all<<<dim3(BATCH / BM, (NTOT + BN - 1) / BN), 512, 0, stream>>>(
        xb8, wb8, biascat, pcat, l5f8, pmax, psum);

    probs_all<<<BATCH, 256, 0, stream>>>(l5f8, out, pcat, pmax, psum, tg, cerow,
                                         j12, j23, j34, j45);

    finalize<<<1, 256, 0, stream>>>(cerow, j45, j34, j23, j12, c45, c34, c23, c12,
                                    out + (size_t)BATCH * NC5);
}

// Round 21
// 339.828 us; speedup vs baseline: 1.0644x; 1.0085x over previous
//
#include <hip/hip_runtime.h>
#include <hip/hip_bf16.h>
#include <stdint.h>

typedef unsigned short u16;
typedef unsigned char u8;
typedef long i64;
typedef float f32x2 __attribute__((ext_vector_type(2)));
typedef float f32x4 __attribute__((ext_vector_type(4)));
typedef unsigned int u32x4 __attribute__((ext_vector_type(4)));

#define FEAT 512
#define BATCH 8192
#define NC1 20
#define NC2 100
#define NC3 500
#define NC4 2000
#define NC5 10000
#define NCAT 2620
#define LDP 2624          // padded leading dim for pcat (fp8 bytes, 16B-clean)
#define NTOT 12620
#define NCT 40            // l5 col tiles (by = 10..49)
#define WN_BLOCKS 3155    // ceil(12620 / 4) wnorm blocks (4 rows x 64 lanes)
#define CAST_BLOCKS 2048  // 8192*512/8/256
#define NGRP 2620         // cosine groups total
#define WCOS_BLOCKS 655   // ceil(2620 / 4)

__device__ inline u16 f2bf(float f) {
    unsigned int u = __builtin_bit_cast(unsigned int, f);
    unsigned int r = (u + 0x7FFFu + ((u >> 16) & 1u)) >> 16;
    return (u16)r;
}
__device__ inline float bfu(u16 u) {
    return __builtin_bit_cast(float, (unsigned int)u << 16);
}
// HW fp8 e4m3 (OCP on gfx950) pack/unpack
__device__ inline unsigned int pack4_fp8(float a0, float a1, float a2, float a3) {
    int v = 0;
    v = __builtin_amdgcn_cvt_pk_fp8_f32(a0, a1, v, false);
    v = __builtin_amdgcn_cvt_pk_fp8_f32(a2, a3, v, true);
    return (unsigned int)v;
}
__device__ inline f32x4 unpack4_fp8(unsigned int v) {
    f32x2 lo = __builtin_amdgcn_cvt_pk_f32_fp8((int)v, false);
    f32x2 hi = __builtin_amdgcn_cvt_pk_f32_fp8((int)v, true);
    f32x4 o; o[0] = lo[0]; o[1] = lo[1]; o[2] = hi[0]; o[3] = hi[1];
    return o;
}
__device__ inline float fp8_1(u8 u) {
    return __builtin_amdgcn_cvt_f32_fp8((int)u, 0);
}

__device__ inline float waveReduceSum(float v) {
    #pragma unroll
    for (int off = 32; off > 0; off >>= 1) v += __shfl_xor(v, off);
    return v;
}
__device__ inline float waveReduceMax(float v) {
    #pragma unroll
    for (int off = 32; off > 0; off >>= 1) v = fmaxf(v, __shfl_xor(v, off));
    return v;
}
// 256-thread blocks
__device__ inline float blockReduceSum(float v, float* sh) {
    int t = threadIdx.x;
    v = waveReduceSum(v);
    __syncthreads();
    if ((t & 63) == 0) sh[t >> 6] = v;
    __syncthreads();
    return sh[0] + sh[1] + sh[2] + sh[3];
}

__device__ inline void gload16(const void* g, void* l) {
    __builtin_amdgcn_global_load_lds((const __attribute__((address_space(1))) void*)g,
                                     (__attribute__((address_space(3))) void*)l, 16, 0, 0);
}

// ---------------- prep: cast x/W to fp8, l2-normalize weights, wcos terms ----------------

__global__ __launch_bounds__(256) void prep(const float* __restrict__ x, u8* __restrict__ xb8,
                                            const float* __restrict__ W1, const float* __restrict__ b1,
                                            const float* __restrict__ W2, const float* __restrict__ b2,
                                            const float* __restrict__ W3, const float* __restrict__ b3,
                                            const float* __restrict__ W4, const float* __restrict__ b4,
                                            const float* __restrict__ W5, const float* __restrict__ b5,
                                            u8* __restrict__ wb8, float* __restrict__ biascat,
                                            float* __restrict__ c45, float* __restrict__ c34,
                                            float* __restrict__ c23, float* __restrict__ c12) {
    int bid = blockIdx.x;
    if (bid < WN_BLOCKS) {
        int r = bid * 4 + (threadIdx.x >> 6);
        if (r >= NTOT) return;
        int t = threadIdx.x & 63;
        const float* W; const float* b; int lr;
        if      (r < 20)   { W = W1; b = b1; lr = r; }
        else if (r < 120)  { W = W2; b = b2; lr = r - 20; }
        else if (r < 620)  { W = W3; b = b3; lr = r - 120; }
        else if (r < 2620) { W = W4; b = b4; lr = r - 620; }
        else               { W = W5; b = b5; lr = r - 2620; }
        const float* p = W + (size_t)lr * FEAT + t * 8;
        float v[8]; float ss = 0.f;
        #pragma unroll
        for (int j = 0; j < 8; ++j) { v[j] = p[j]; ss += v[j] * v[j]; }
        ss = waveReduceSum(ss);
        float inv = 1.0f / fmaxf(sqrtf(ss), 1e-12f);
        uint2 o;
        o.x = pack4_fp8(v[0] * inv, v[1] * inv, v[2] * inv, v[3] * inv);
        o.y = pack4_fp8(v[4] * inv, v[5] * inv, v[6] * inv, v[7] * inv);
        *reinterpret_cast<uint2*>(wb8 + (size_t)r * FEAT + t * 8) = o;
        if (t == 0) biascat[r] = b[lr];
    } else if (bid < WN_BLOCKS + CAST_BLOCKS) {
        int i = (bid - WN_BLOCKS) * 256 + threadIdx.x;
        const float* p = x + (size_t)i * 8;
        uint2 o;
        o.x = pack4_fp8(p[0], p[1], p[2], p[3]);
        o.y = pack4_fp8(p[4], p[5], p[6], p[7]);
        *reinterpret_cast<uint2*>(xb8 + (size_t)i * 8) = o;
    } else {
        // weight-cosine terms: one wave per group, 4 groups per block (raw f32 W)
        int g = (bid - WN_BLOCKS - CAST_BLOCKS) * 4 + (threadIdx.x >> 6);
        if (g >= NGRP) return;
        int t = threadIdx.x & 63;
        const float* Wp; const float* Wc; int fan, j; float* dst;
        if      (g < 2000) { Wp = W4; Wc = W5; fan = 5; dst = c45; j = g; }
        else if (g < 2500) { Wp = W3; Wc = W4; fan = 4; dst = c34; j = g - 2000; }
        else if (g < 2600) { Wp = W2; Wc = W3; fan = 5; dst = c23; j = g - 2500; }
        else               { Wp = W1; Wc = W2; fan = 5; dst = c12; j = g - 2600; }

        float hat[8] = {0, 0, 0, 0, 0, 0, 0, 0};
        for (int c = 0; c < fan; ++c) {
            const float* cr = Wc + ((size_t)(j * fan + c)) * FEAT + t * 8;
            float v[8]; float ss = 0.f;
            #pragma unroll
            for (int i = 0; i < 8; ++i) { v[i] = cr[i]; ss += v[i] * v[i]; }
            ss = waveReduceSum(ss);
            float inv = 1.0f / fmaxf(sqrtf(ss), 1e-12f);
            #pragma unroll
            for (int i = 0; i < 8; ++i) hat[i] += v[i] * inv;
        }
        float hs = 0.f;
        #pragma unroll
        for (int i = 0; i < 8; ++i) hs += hat[i] * hat[i];
        hs = waveReduceSum(hs);
        float hinv = 1.0f / fmaxf(sqrtf(hs), 1e-12f);
        const float* pr = Wp + (size_t)j * FEAT + t * 8;
        float ps = 0.f, dot = 0.f;
        #pragma unroll
        for (int i = 0; i < 8; ++i) { float pv = pr[i]; ps += pv * pv; dot += pv * hat[i]; }
        ps = waveReduceSum(ps);
        dot = waveReduceSum(dot);
        if (t == 0) dst[j] = dot * hinv / fmaxf(sqrtf(ps), 1e-12f);
    }
}

// ---------------- fp8 GEMM over all 12620 columns (unchanged from R19) ----------------

#define BM 256
#define BN 256
#define BK 64
#define KITERS (FEAT / BK)

__global__ __launch_bounds__(512, 2) void gemm_all(const u8* __restrict__ A, const u8* __restrict__ Bw,
                                                   const float* __restrict__ bias,
                                                   u8* __restrict__ pcat, u8* __restrict__ l5f8,
                                                   float* __restrict__ pmax, float* __restrict__ psum) {
    __shared__ uint4 sABq[2][2048];            // 2 x 32 KB double buffer
    const int t = threadIdx.x;
    const int lane = t & 63, wid = t >> 6;
    const int lane15 = lane & 15, q = lane >> 4;
    const int wr = wid >> 2, wcol = wid & 3;

    // XCD-aware bijective swizzle (nwg = 32*50 = 1600, %8 == 0)
    int nwg = gridDim.x * gridDim.y;
    int lid = blockIdx.y * gridDim.x + blockIdx.x;
    int cpx = nwg >> 3;
    int swz = (lid & 7) * cpx + (lid >> 3);
    int bx = swz % gridDim.x, by = swz / gridDim.x;
    const int r0 = bx * BM, c0 = by * BN;

    f32x4 acc[8][4];
    #pragma unroll
    for (int m = 0; m < 8; ++m)
        #pragma unroll
        for (int n = 0; n < 4; ++n) acc[m][n] = f32x4{0.f, 0.f, 0.f, 0.f};

    // stage one unit (region, kh): 512 chunks of 16B, 1 per thread, LINEAR dest
    auto stageUnit = [&](char* nb, int region, int kh, int ktB) {
        int row = t & 255, p = t >> 8;
        int srck = ktB + kh * 32 + p * 16;
        const u8* g;
        if (region == 0) {
            g = A + (size_t)(r0 + row) * FEAT + srck;
        } else {
            int br = c0 + row; if (br >= NTOT) br = NTOT - 1;
            g = Bw + (size_t)br * FEAT + srck;
        }
        gload16(g, nb + region * 16384 + kh * 8192 + (size_t)t * 16);
    };

    // fragment reads: 8 fp8 (b64) at row r; k offset q*8 = (q>>1)*16 + (q&1)*8
    auto readA = [&](char* sb, int ks, int mh, i64* af) {
        #pragma unroll
        for (int i = 0; i < 4; ++i) {
            int row = wr * 128 + (mh * 4 + i) * 16 + lane15;
            af[i] = *reinterpret_cast<const i64*>(sb + ks * 8192 + (q >> 1) * 4096 +
                                                  row * 16 + (q & 1) * 8);
        }
    };
    auto readB = [&](char* sb, int ks, i64* bv) {
        #pragma unroll
        for (int n = 0; n < 4; ++n) {
            int row = wcol * 64 + n * 16 + lane15;
            bv[n] = *reinterpret_cast<const i64*>(sb + 16384 + ks * 8192 + (q >> 1) * 4096 +
                                                  row * 16 + (q & 1) * 8);
        }
    };

    // prologue: tile 0's four units, oldest-first {A-k0, B-k0, A-k1, B-k1}
    {
        char* nb = (char*)sABq[0];
        stageUnit(nb, 0, 0, 0);
        stageUnit(nb, 1, 0, 0);
        stageUnit(nb, 0, 1, 0);
        stageUnit(nb, 1, 1, 0);
    }

    for (int T = 0; T < KITERS; ++T) {
        char* sb = (char*)sABq[T & 1];
        char* nb = (char*)sABq[(T + 1) & 1];
        const bool more = (T + 1 < KITERS);
        const int ktB = (T + 1) * BK;

        // ---- k-half 0 ----
        asm volatile("s_waitcnt vmcnt(2)" ::: "memory");
        __builtin_amdgcn_sched_barrier(0);
        __builtin_amdgcn_s_barrier();
        __builtin_amdgcn_sched_barrier(0);
        {
            i64 bv[4], af[4];
            readB(sb, 0, bv);
            readA(sb, 0, 0, af);
            if (more) stageUnit(nb, 0, 0, ktB);
            __builtin_amdgcn_sched_barrier(0);
            __builtin_amdgcn_s_setprio(1);
            #pragma unroll
            for (int i = 0; i < 4; ++i)
                #pragma unroll
                for (int n = 0; n < 4; ++n)
                    acc[i][n] = __builtin_amdgcn_mfma_f32_16x16x32_fp8_fp8(bv[n], af[i], acc[i][n], 0, 0, 0);
            __builtin_amdgcn_s_setprio(0);
            __builtin_amdgcn_sched_barrier(0);
            readA(sb, 0, 1, af);
            if (more) stageUnit(nb, 1, 0, ktB);
            __builtin_amdgcn_sched_barrier(0);
            __builtin_amdgcn_s_setprio(1);
            #pragma unroll
            for (int i = 0; i < 4; ++i)
                #pragma unroll
                for (int n = 0; n < 4; ++n)
                    acc[4 + i][n] = __builtin_amdgcn_mfma_f32_16x16x32_fp8_fp8(bv[n], af[i], acc[4 + i][n], 0, 0, 0);
            __builtin_amdgcn_s_setprio(0);
            __builtin_amdgcn_sched_barrier(0);
        }

        // ---- k-half 1 ----
        if (more) { asm volatile("s_waitcnt vmcnt(2)" ::: "memory"); }
        else      { asm volatile("s_waitcnt vmcnt(0)" ::: "memory"); }
        __builtin_amdgcn_sched_barrier(0);
        __builtin_amdgcn_s_barrier();
        __builtin_amdgcn_sched_barrier(0);
        {
            i64 bv[4], af[4];
            readB(sb, 1, bv);
            readA(sb, 1, 0, af);
            if (more) stageUnit(nb, 0, 1, ktB);
            __builtin_amdgcn_sched_barrier(0);
            __builtin_amdgcn_s_setprio(1);
            #pragma unroll
            for (int i = 0; i < 4; ++i)
                #pragma unroll
                for (int n = 0; n < 4; ++n)
                    acc[i][n] = __builtin_amdgcn_mfma_f32_16x16x32_fp8_fp8(bv[n], af[i], acc[i][n], 0, 0, 0);
            __builtin_amdgcn_s_setprio(0);
            __builtin_amdgcn_sched_barrier(0);
            readA(sb, 1, 1, af);
            if (more) stageUnit(nb, 1, 1, ktB);
            __builtin_amdgcn_sched_barrier(0);
            __builtin_amdgcn_s_setprio(1);
            #pragma unroll
            for (int i = 0; i < 4; ++i)
                #pragma unroll
                for (int n = 0; n < 4; ++n)
                    acc[4 + i][n] = __builtin_amdgcn_mfma_f32_16x16x32_fp8_fp8(bv[n], af[i], acc[4 + i][n], 0, 0, 0);
            __builtin_amdgcn_s_setprio(0);
            __builtin_amdgcn_sched_barrier(0);
        }
    }

    // transposed D layout: lane holds row = r0+wr*128+m*16+lane15,
    // cols cb..cb+3 with cb = c0+wcol*64+n*16+q*4
    bool vld[4], svld[4]; int cb[4];
    #pragma unroll
    for (int n = 0; n < 4; ++n) {
        cb[n] = c0 + wcol * 64 + n * 16 + q * 4;
        vld[n] = (cb[n] < NTOT);
        svld[n] = vld[n] && (cb[n] >= NCAT);
        if (vld[n]) {
            float b0 = bias[cb[n]], b1 = bias[cb[n] + 1], b2 = bias[cb[n] + 2], b3 = bias[cb[n] + 3];
            #pragma unroll
            for (int m = 0; m < 8; ++m) {
                acc[m][n][0] += b0; acc[m][n][1] += b1;
                acc[m][n][2] += b2; acc[m][n][3] += b3;
            }
        }
    }

    if (by >= 10) {   // softmax partials for the l5 region
        float* fmx = (float*)sABq;           // [256][4] row-max per wcol
        float* fsm = fmx + 1024;             // [256][4] row-sumexp per wcol
        float bm[8];
        #pragma unroll
        for (int m = 0; m < 8; ++m) {
            float v = -1e30f;
            #pragma unroll
            for (int n = 0; n < 4; ++n)
                if (svld[n]) {
                    #pragma unroll
                    for (int j = 0; j < 4; ++j) v = fmaxf(v, acc[m][n][j]);
                }
            v = fmaxf(v, __shfl_xor(v, 16));
            v = fmaxf(v, __shfl_xor(v, 32));
            bm[m] = v;
        }
        __syncthreads();
        if (lane < 16) {
            #pragma unroll
            for (int m = 0; m < 8; ++m)
                fmx[(wr * 128 + m * 16 + lane15) * 4 + wcol] = bm[m];
        }
        __syncthreads();
        #pragma unroll
        for (int m = 0; m < 8; ++m) {
            int row = wr * 128 + m * 16 + lane15;
            bm[m] = fmaxf(fmaxf(fmx[row * 4], fmx[row * 4 + 1]),
                          fmaxf(fmx[row * 4 + 2], fmx[row * 4 + 3]));
        }
        float sm[8];
        #pragma unroll
        for (int m = 0; m < 8; ++m) {
            float s = 0.f;
            #pragma unroll
            for (int n = 0; n < 4; ++n)
                if (svld[n]) {
                    #pragma unroll
                    for (int j = 0; j < 4; ++j) s += __expf(acc[m][n][j] - bm[m]);
                }
            s += __shfl_xor(s, 16);
            s += __shfl_xor(s, 32);
            sm[m] = s;
        }
        if (lane < 16) {
            #pragma unroll
            for (int m = 0; m < 8; ++m)
                fsm[(wr * 128 + m * 16 + lane15) * 4 + wcol] = sm[m];
        }
        __syncthreads();
        if (t < 256) {
            float m4 = fmaxf(fmaxf(fmx[t * 4], fmx[t * 4 + 1]), fmaxf(fmx[t * 4 + 2], fmx[t * 4 + 3]));
            float s4 = fsm[t * 4] + fsm[t * 4 + 1] + fsm[t * 4 + 2] + fsm[t * 4 + 3];
            size_t idx = (size_t)(r0 + t) * NCT + (by - 10);
            pmax[idx] = m4;
            psum[idx] = s4;
        }
    }

    // store: both regions fp8 as HW-packed uint (4 cols x 1B)
    #pragma unroll
    for (int m = 0; m < 8; ++m) {
        int row = r0 + wr * 128 + m * 16 + lane15;
        #pragma unroll
        for (int n = 0; n < 4; ++n) {
            if (vld[n]) {
                unsigned int v = pack4_fp8(acc[m][n][0], acc[m][n][1], acc[m][n][2], acc[m][n][3]);
                u8* dst = (cb[n] < NCAT)
                    ? &pcat[(size_t)row * LDP + cb[n]]
                    : &l5f8[(size_t)row * NC5 + (cb[n] - NCAT)];
                *reinterpret_cast<unsigned int*>(dst) = v;
            }
        }
    }
}

// ---------------- fused LSE + CE + probabilities + all JSDs ----------------
// 256-thread block per row; softmax segments distributed across waves with
// each segment owned by EXACTLY ONE wave (no duplicate read-modify-write).

__global__ __launch_bounds__(256) void probs_all(const u8* __restrict__ l5f8, float* __restrict__ out,
                                                 const u8* __restrict__ pcat,
                                                 const float* __restrict__ pmax, const float* __restrict__ psum,
                                                 const int* __restrict__ tgt,
                                                 float* __restrict__ cerow,
                                                 float* __restrict__ j12, float* __restrict__ j23,
                                                 float* __restrict__ j34, float* __restrict__ j45) {
    __shared__ u16 P5[NC5];
    __shared__ float PC[LDP];
    __shared__ float sh[4];
    __shared__ float shls;
    int b = blockIdx.x, t = threadIdx.x;
    int w = t >> 6, lane = t & 63;
    float* orow = out + (size_t)b * NC5;
    const u8* lrow = l5f8 + (size_t)b * NC5;
    const u8* prow = pcat + (size_t)b * LDP;

    // wave 0: reduce the per-coltile partials into the row LSE
    if (t < 64) {
        float pm = (t < NCT) ? pmax[(size_t)b * NCT + t] : -1e30f;
        float ps = (t < NCT) ? psum[(size_t)b * NCT + t] : 0.f;
        float gm = waveReduceMax(pm);
        float s = waveReduceSum(ps * __expf(pm - gm));
        if (t == 0) {
            float ls = gm + __logf(s);
            shls = ls;
            int tg = tgt[b];
            cerow[b] = -(fp8_1(lrow[tg]) - ls);
        }
    }
    // stage pcat row (fp8) into LDS as f32: 328 items of 8
    for (int c = t; c < LDP / 8; c += 256) {
        uint2 raw = ((const uint2*)prow)[c];
        f32x4 a = unpack4_fp8(raw.x);
        f32x4 bb = unpack4_fp8(raw.y);
        int base = c * 8;
        #pragma unroll
        for (int k = 0; k < 4; ++k) PC[base + k] = a[k];
        #pragma unroll
        for (int k = 0; k < 4; ++k) PC[base + 4 + k] = bb[k];
    }
    __syncthreads();
    float ls = shls;

    // l5 row: 1250 items of 8 fp8 (uint2 cached load); two f32x4 NT stores
    for (int c = t; c < NC5 / 8; c += 256) {
        uint2 raw = ((const uint2*)lrow)[c];
        f32x4 l0 = unpack4_fp8(raw.x);
        f32x4 l1 = unpack4_fp8(raw.y);
        f32x4 o0, o1;
        #pragma unroll
        for (int k = 0; k < 4; ++k) o0[k] = __expf(l0[k] - ls);
        #pragma unroll
        for (int k = 0; k < 4; ++k) o1[k] = __expf(l1[k] - ls);
        __builtin_nontemporal_store(o0, &((f32x4*)orow)[c * 2]);
        __builtin_nontemporal_store(o1, &((f32x4*)orow)[c * 2 + 1]);
        union { u16 u[8]; uint4 v; } pk;
        #pragma unroll
        for (int k = 0; k < 4; ++k) pk.u[k] = f2bf(o0[k]);
        #pragma unroll
        for (int k = 0; k < 4; ++k) pk.u[4 + k] = f2bf(o1[k]);
        ((uint4*)P5)[c] = pk.v;
    }
    __syncthreads();

    // ---- wave-parallel softmax over PC segments, one OWNER wave each ----
    // wave 0: {0,20}+{20,100}; wave 1: {120,500}; wave 2: {620,2000}; wave 3 idle.
    auto wave_softmax = [&](int off, int C) {
        float m = -1e30f;
        for (int c = lane; c < C; c += 64) m = fmaxf(m, PC[off + c]);
        m = waveReduceMax(m);
        float s = 0.f;
        for (int c = lane; c < C; c += 64) s += __expf(PC[off + c] - m);
        s = waveReduceSum(s);
        float inv = 1.0f / s;
        for (int c = lane; c < C; c += 64) PC[off + c] = __expf(PC[off + c] - m) * inv;
    };
    if (w == 0) { wave_softmax(0, NC1); wave_softmax(20, NC2); }
    else if (w == 1) { wave_softmax(120, NC3); }
    else if (w == 2) { wave_softmax(620, NC4); }
    __syncthreads();

    // ---- wave-parallel JSD terms (read-only on PC; race-free) ----
    // wave 0: j12 + j23; wave 1: j34; wave 2: j45 lower half; wave 3: upper half.
    auto jsd_wave = [&](int childOff, int fan, int parentOff, int gLo, int gHi) {
        float klpm = 0.f, klqm = 0.f;
        for (int g = gLo + lane; g < gHi; g += 64) {
            float qv = 0.f;
            for (int f = 0; f < fan; ++f) qv += PC[childOff + g * fan + f];
            float pp = PC[parentOff + g];
            float mm = 0.5f * (qv + pp);
            float lm = __logf(mm + 1e-8f);
            klpm += qv * (__logf(qv + 1e-8f) - lm);
            klqm += pp * (__logf(pp + 1e-8f) - lm);
        }
        return waveReduceSum(0.5f * (klpm + klqm));
    };
    if (w == 0) {
        float v12 = jsd_wave(20, 5, 0, 0, NC1);
        float v23 = jsd_wave(120, 5, 20, 0, NC2);
        if (lane == 0) { j12[b] = v12; j23[b] = v23; }
    } else if (w == 1) {
        float v34 = jsd_wave(620, 4, 120, 0, NC3);
        if (lane == 0) j34[b] = v34;
    } else {
        // jsd45: agg p5 (fan 5, from bf16 P5) vs p4; waves 2/3 split halves
        int gLo = (w == 2) ? 0 : NC4 / 2;
        int gHi = (w == 2) ? NC4 / 2 : NC4;
        float klpm = 0.f, klqm = 0.f;
        for (int g = gLo + lane; g < gHi; g += 64) {
            float qv = 0.f;
            #pragma unroll
            for (int f = 0; f < 5; ++f) qv += bfu(P5[5 * g + f]);
            float pp = PC[620 + g];
            float mm = 0.5f * (qv + pp);
            float lm = __logf(mm + 1e-8f);
            klpm += qv * (__logf(qv + 1e-8f) - lm);
            klqm += pp * (__logf(pp + 1e-8f) - lm);
        }
        float part = waveReduceSum(0.5f * (klpm + klqm));
        if (lane == 0) sh[w - 2] = part;
    }
    __syncthreads();
    if (t == 0) j45[b] = sh[0] + sh[1];
}

__global__ __launch_bounds__(256) void finalize(const float* __restrict__ ce, const float* __restrict__ j45,
                                                const float* __restrict__ j34, const float* __restrict__ j23,
                                                const float* __restrict__ j12, const float* __restrict__ c45,
                                                const float* __restrict__ c34, const float* __restrict__ c23,
                                                const float* __restrict__ c12, float* __restrict__ lossOut) {
    __shared__ float sh[4];
    auto meanArr = [&](const float* a, int n) {
        float s = 0.f;
        for (int i = threadIdx.x; i < n; i += 256) s += a[i];
        s = blockReduceSum(s, sh);
        return s / n;
    };
    float loss = meanArr(ce, BATCH);
    loss += meanArr(j45, BATCH) + meanArr(j34, BATCH) + meanArr(j23, BATCH) + meanArr(j12, BATCH);
    loss -= meanArr(c45, NC4) + meanArr(c34, NC3) + meanArr(c23, NC2) + meanArr(c12, NC1);
    if (threadIdx.x == 0) *lossOut = loss;
}

// ---------------- launch ----------------

extern "C" void kernel_launch(void* const* d_in, const int* in_sizes, int n_in,
                              void* d_out, int out_size, void* d_ws, size_t ws_size,
                              hipStream_t stream) {
    const float* x  = (const float*)d_in[0];
    const int*   tg = (const int*)d_in[1];
    const float* W1 = (const float*)d_in[2];  const float* b1 = (const float*)d_in[3];
    const float* W2 = (const float*)d_in[4];  const float* b2 = (const float*)d_in[5];
    const float* W3 = (const float*)d_in[6];  const float* b3 = (const float*)d_in[7];
    const float* W4 = (const float*)d_in[8];  const float* b4 = (const float*)d_in[9];
    const float* W5 = (const float*)d_in[10]; const float* b5 = (const float*)d_in[11];
    float* out = (float*)d_out;

    char* ws = (char*)d_ws;
    size_t off = 0;
    auto alloc = [&](size_t bytes) { void* p = ws + off; off = (off + bytes + 255) & ~(size_t)255; return p; };
    u8*    xb8     = (u8*)alloc((size_t)BATCH * FEAT);
    u8*    wb8     = (u8*)alloc((size_t)NTOT * FEAT);
    float* biascat = (float*)alloc((size_t)NTOT * 4);
    u8*    pcat    = (u8*)alloc((size_t)BATCH * LDP);
    u8*    l5f8    = (u8*)alloc((size_t)BATCH * NC5);
    float* pmax    = (float*)alloc((size_t)BATCH * NCT * 4);
    float* psum    = (float*)alloc((size_t)BATCH * NCT * 4);
    float* cerow   = (float*)alloc((size_t)BATCH * 4);
    float* j45     = (float*)alloc((size_t)BATCH * 4);
    float* j34     = (float*)alloc((size_t)BATCH * 4);
    float* j23     = (float*)alloc((size_t)BATCH * 4);
    float* j12     = (float*)alloc((size_t)BATCH * 4);
    float* c45     = (float*)alloc((size_t)NC4 * 4);
    float* c34     = (float*)alloc((size_t)NC3 * 4);
    float* c23     = (float*)alloc((size_t)NC2 * 4);
    float* c12     = (float*)alloc((size_t)NC1 * 4);

    prep<<<WN_BLOCKS + CAST_BLOCKS + WCOS_BLOCKS, 256, 0, stream>>>(
        x, xb8, W1, b1, W2, b2, W3, b3, W4, b4, W5, b5, wb8, biascat, c45, c34, c23, c12);

    gemm_all<<<dim3(BATCH / BM, (NTOT + BN - 1) / BN), 512, 0, stream>>>(
        xb8, wb8, biascat, pcat, l5f8, pmax, psum);

    probs_all<<<BATCH, 256, 0, stream>>>(l5f8, out, pcat, pmax, psum, tg, cerow,
                                         j12, j23, j34, j45);

    finalize<<<1, 256, 0, stream>>>(cerow, j45, j34, j23, j12, c45, c34, c23, c12,
                                    out + (size_t)BATCH * NC5);
}